// Round 1
// baseline (3500.890 us; speedup 1.0000x reference)
//
#include <hip/hip_runtime.h>
#include <math.h>

#define BATCH 8192
#define DDIM 256
#define HDIM 266
#define HP 272          // padded H (multiple of 16), row stride for hidden buffers
#define TSTEPS 20
#define BN_EPS 1e-5f
#define LAMBDA_C 1.0f
#define SIGMA_C 1.0f

// ---------------------------------------------------------------------------
// Fused GEMM: C[M,N] = act(A)[M,K] @ W[N,K]^T + bias, M = BATCH fixed.
// Optional BN+ReLU applied to A while staging (params built from raw column
// sum/sumsq accumulators of the producer layer). Epilogue accumulates column
// sum/sumsq of C into csum_out/csq_out (for the next layer's BN).
// Tiles: 64x64 block, BK=16, 256 threads, 4x4 per thread.
// ---------------------------------------------------------------------------
template<bool BN_IN>
__global__ __launch_bounds__(256)
void gemm_stats_k(const float* __restrict__ A, int lda, int Kdim,
                  const float* __restrict__ W, int ldw,
                  const float* __restrict__ bias, int Ndim,
                  const float* __restrict__ csum_in, const float* __restrict__ csq_in,
                  const float* __restrict__ gin, const float* __restrict__ bein,
                  float* __restrict__ C, int ldc,
                  float* __restrict__ csum_out, float* __restrict__ csq_out)
{
    __shared__ float As[16][68];
    __shared__ float Ws[16][68];
    __shared__ float sBN[HP];
    __shared__ float tBN[HP];

    const int tid = threadIdx.x;
    const int tx = tid & 15;
    const int ty = tid >> 4;
    const int col0 = blockIdx.x * 64;
    const int row0 = blockIdx.y * 64;

    if (BN_IN) {
        for (int k = tid; k < Kdim; k += 256) {
            float m  = csum_in[k] * (1.0f / BATCH);
            float v  = csq_in[k] * (1.0f / BATCH) - m * m;
            float rs = rsqrtf(fmaxf(v, 0.0f) + BN_EPS);
            float s  = gin[k] * rs;
            sBN[k] = s;
            tBN[k] = bein[k] - m * s;
        }
        __syncthreads();
    }

    float acc[4][4];
    #pragma unroll
    for (int r = 0; r < 4; ++r)
        #pragma unroll
        for (int c = 0; c < 4; ++c) acc[r][c] = 0.0f;

    const int kk = tid & 15;   // k within tile
    const int rb = tid >> 4;   // row/col base for staging
    const int kTiles = (Kdim + 15) >> 4;

    for (int kt = 0; kt < kTiles; ++kt) {
        const int k = kt * 16 + kk;
        const bool kv = (k < Kdim);
        #pragma unroll
        for (int q = 0; q < 4; ++q) {
            int r = rb + q * 16;
            float av = 0.0f;
            if (kv) {
                av = A[(size_t)(row0 + r) * lda + k];
                if (BN_IN) av = fmaxf(av * sBN[k] + tBN[k], 0.0f);
            }
            As[kk][r] = av;
            int n = col0 + r;
            float wv = 0.0f;
            if (kv && n < Ndim) wv = W[(size_t)n * ldw + k];
            Ws[kk][r] = wv;
        }
        __syncthreads();
        #pragma unroll
        for (int k2 = 0; k2 < 16; ++k2) {
            float a[4], w[4];
            #pragma unroll
            for (int r = 0; r < 4; ++r) a[r] = As[k2][ty * 4 + r];
            #pragma unroll
            for (int c = 0; c < 4; ++c) w[c] = Ws[k2][tx * 4 + c];
            #pragma unroll
            for (int r = 0; r < 4; ++r)
                #pragma unroll
                for (int c = 0; c < 4; ++c)
                    acc[r][c] = fmaf(a[r], w[c], acc[r][c]);
        }
        __syncthreads();
    }

    // Epilogue: bias + store + per-column partial stats
    float cv[4][4];
    #pragma unroll
    for (int c = 0; c < 4; ++c) {
        int n = col0 + tx * 4 + c;
        float bv = (n < Ndim) ? bias[n] : 0.0f;
        #pragma unroll
        for (int r = 0; r < 4; ++r) {
            float v = acc[r][c] + bv;
            cv[r][c] = v;
            if (n < Ndim) C[(size_t)(row0 + ty * 4 + r) * ldc + n] = v;
        }
    }

    float sc[4], qc[4];
    #pragma unroll
    for (int c = 0; c < 4; ++c) {
        float s = 0.0f, q = 0.0f;
        #pragma unroll
        for (int r = 0; r < 4; ++r) { s += cv[r][c]; q += cv[r][c] * cv[r][c]; }
        sc[c] = s; qc[c] = q;
    }
    float* red = &As[0][0];  // 16*68 = 1088 floats >= 64*17
    #pragma unroll
    for (int c = 0; c < 4; ++c) red[(tx * 4 + c) * 17 + ty] = sc[c];
    __syncthreads();
    if (tid < 64) {
        float s = 0.0f;
        #pragma unroll
        for (int j = 0; j < 16; ++j) s += red[tid * 17 + j];
        if (col0 + tid < Ndim) atomicAdd(&csum_out[col0 + tid], s);
    }
    __syncthreads();
    #pragma unroll
    for (int c = 0; c < 4; ++c) red[(tx * 4 + c) * 17 + ty] = qc[c];
    __syncthreads();
    if (tid < 64) {
        float q = 0.0f;
        #pragma unroll
        for (int j = 0; j < 16; ++j) q += red[tid * 17 + j];
        if (col0 + tid < Ndim) atomicAdd(&csq_out[col0 + tid], q);
    }
}

// ---------------------------------------------------------------------------
// Step layer 3: grad = bnrelu(h2) @ W3^T + b3 (N = 256 exact), then SDE update:
//   noise = sigma*sqrt(ht)*xi;  xt += -sqrt(L)*grad*ht + noise
//   frow += L*grad^2 (row sum);  dotrow += grad*noise (row sum)
// ---------------------------------------------------------------------------
__global__ __launch_bounds__(256)
void gemm_step3_k(const float* __restrict__ A,        // hpre2, stride HP, K=HDIM
                  const float* __restrict__ W,        // W3_t [DDIM, HDIM]
                  const float* __restrict__ bias,     // b3_t [DDIM]
                  const float* __restrict__ csum_in, const float* __restrict__ csq_in,
                  const float* __restrict__ gin, const float* __restrict__ bein,
                  const float* __restrict__ xi_t,     // [BATCH, DDIM]
                  float* __restrict__ xt,             // [BATCH, DDIM] (in d_out)
                  float* __restrict__ frow, float* __restrict__ dotrow,
                  const float* __restrict__ tg, int t)
{
    __shared__ float As[16][68];
    __shared__ float Ws[16][68];
    __shared__ float sBN[HP];
    __shared__ float tBN[HP];

    const int tid = threadIdx.x;
    const int tx = tid & 15;
    const int ty = tid >> 4;
    const int col0 = blockIdx.x * 64;
    const int row0 = blockIdx.y * 64;

    for (int k = tid; k < HDIM; k += 256) {
        float m  = csum_in[k] * (1.0f / BATCH);
        float v  = csq_in[k] * (1.0f / BATCH) - m * m;
        float rs = rsqrtf(fmaxf(v, 0.0f) + BN_EPS);
        float s  = gin[k] * rs;
        sBN[k] = s;
        tBN[k] = bein[k] - m * s;
    }
    __syncthreads();

    float acc[4][4];
    #pragma unroll
    for (int r = 0; r < 4; ++r)
        #pragma unroll
        for (int c = 0; c < 4; ++c) acc[r][c] = 0.0f;

    const int kk = tid & 15;
    const int rb = tid >> 4;
    const int kTiles = (HDIM + 15) >> 4;  // 17

    for (int kt = 0; kt < kTiles; ++kt) {
        const int k = kt * 16 + kk;
        const bool kv = (k < HDIM);
        #pragma unroll
        for (int q = 0; q < 4; ++q) {
            int r = rb + q * 16;
            float av = 0.0f;
            if (kv) {
                av = A[(size_t)(row0 + r) * HP + k];
                av = fmaxf(av * sBN[k] + tBN[k], 0.0f);
            }
            As[kk][r] = av;
            int n = col0 + r;   // n < 256 always valid (DDIM=256, 4 col tiles)
            float wv = kv ? W[(size_t)n * HDIM + k] : 0.0f;
            Ws[kk][r] = wv;
        }
        __syncthreads();
        #pragma unroll
        for (int k2 = 0; k2 < 16; ++k2) {
            float a[4], w[4];
            #pragma unroll
            for (int r = 0; r < 4; ++r) a[r] = As[k2][ty * 4 + r];
            #pragma unroll
            for (int c = 0; c < 4; ++c) w[c] = Ws[k2][tx * 4 + c];
            #pragma unroll
            for (int r = 0; r < 4; ++r)
                #pragma unroll
                for (int c = 0; c < 4; ++c)
                    acc[r][c] = fmaf(a[r], w[c], acc[r][c]);
        }
        __syncthreads();
    }

    const float ht = tg[t + 1] - tg[t];
    const float sn = SIGMA_C * sqrtf(ht);
    const float sql = sqrtf(LAMBDA_C);

    float fp[4] = {0.f, 0.f, 0.f, 0.f};
    float dp[4] = {0.f, 0.f, 0.f, 0.f};
    #pragma unroll
    for (int c = 0; c < 4; ++c) {
        int col = col0 + tx * 4 + c;
        float bv = bias[col];
        #pragma unroll
        for (int r = 0; r < 4; ++r) {
            int row = row0 + ty * 4 + r;
            float grad = acc[r][c] + bv;
            size_t idx = (size_t)row * DDIM + col;
            float noise = sn * xi_t[idx];
            xt[idx] = xt[idx] - sql * grad * ht + noise;
            fp[r] += LAMBDA_C * grad * grad;
            dp[r] += grad * noise;
        }
    }
    // reduce across tx (16 consecutive lanes within a wave share a row group)
    #pragma unroll
    for (int r = 0; r < 4; ++r) {
        fp[r] += __shfl_xor(fp[r], 1);  dp[r] += __shfl_xor(dp[r], 1);
        fp[r] += __shfl_xor(fp[r], 2);  dp[r] += __shfl_xor(dp[r], 2);
        fp[r] += __shfl_xor(fp[r], 4);  dp[r] += __shfl_xor(dp[r], 4);
        fp[r] += __shfl_xor(fp[r], 8);  dp[r] += __shfl_xor(dp[r], 8);
        if (tx == 0) {
            atomicAdd(&frow[row0 + ty * 4 + r], fp[r]);
            atomicAdd(&dotrow[row0 + ty * 4 + r], dp[r]);
        }
    }
}

// ---------------------------------------------------------------------------
// v-net layer 3: pre3[i] = bnrelu(h2v)[i,:] . vW3 + vb3  (one wave per row),
// accumulate batch sum/sumsq of pre3.
// ---------------------------------------------------------------------------
__global__ __launch_bounds__(256)
void vrow_k(const float* __restrict__ hpre2,
            const float* __restrict__ csum_in, const float* __restrict__ csq_in,
            const float* __restrict__ gin, const float* __restrict__ bein,
            const float* __restrict__ vW3, const float* __restrict__ vb3,
            float* __restrict__ pre3, float* __restrict__ sum3, float* __restrict__ sumsq3)
{
    __shared__ float sBN[HDIM];
    __shared__ float tBN[HDIM];
    __shared__ float wred[8];
    const int tid = threadIdx.x;
    for (int k = tid; k < HDIM; k += 256) {
        float m  = csum_in[k] * (1.0f / BATCH);
        float v  = csq_in[k] * (1.0f / BATCH) - m * m;
        float rs = rsqrtf(fmaxf(v, 0.0f) + BN_EPS);
        float s  = gin[k] * rs;
        sBN[k] = s;
        tBN[k] = bein[k] - m * s;
    }
    __syncthreads();
    const int wave = tid >> 6, lane = tid & 63;
    const int row = blockIdx.x * 4 + wave;
    float sum = 0.0f;
    for (int k = lane; k < HDIM; k += 64) {
        float v = fmaxf(hpre2[(size_t)row * HP + k] * sBN[k] + tBN[k], 0.0f);
        sum += v * vW3[k];
    }
    sum += __shfl_xor(sum, 1);  sum += __shfl_xor(sum, 2);
    sum += __shfl_xor(sum, 4);  sum += __shfl_xor(sum, 8);
    sum += __shfl_xor(sum, 16); sum += __shfl_xor(sum, 32);
    if (lane == 0) {
        float p = sum + vb3[0];
        pre3[row] = p;
        wred[wave] = p;
        wred[4 + wave] = p * p;
    }
    __syncthreads();
    if (tid == 0) {
        atomicAdd(sum3,   wred[0] + wred[1] + wred[2] + wred[3]);
        atomicAdd(sumsq3, wred[4] + wred[5] + wred[6] + wred[7]);
    }
}

// v-net layer-3 BN+ReLU -> vt; also reset column-stat accumulators for the scan
__global__ __launch_bounds__(256)
void v3b_k(const float* __restrict__ pre3,
           const float* __restrict__ sum3, const float* __restrict__ sumsq3,
           const float* __restrict__ vg3, const float* __restrict__ vbe3,
           float* __restrict__ vt,
           float* __restrict__ csA, float* __restrict__ cqA,
           float* __restrict__ csB, float* __restrict__ cqB)
{
    int i = blockIdx.x * 256 + threadIdx.x;
    float m  = sum3[0] * (1.0f / BATCH);
    float va = fmaxf(sumsq3[0] * (1.0f / BATCH) - m * m, 0.0f);
    float rs = rsqrtf(va + BN_EPS);
    if (i < BATCH) vt[i] = fmaxf(vg3[0] * (pre3[i] - m) * rs + vbe3[0], 0.0f);
    if (i < HP) { csA[i] = 0.0f; cqA[i] = 0.0f; csB[i] = 0.0f; cqB[i] = 0.0f; }
}

// per-step v update: vt += -f*ht + dot; write v to d_out; reset accumulators
__global__ __launch_bounds__(256)
void step_final_k(const float* __restrict__ tg, int t,
                  float* __restrict__ vt,
                  float* __restrict__ frow, float* __restrict__ dotrow,
                  float* __restrict__ outv,
                  float* __restrict__ csA, float* __restrict__ cqA,
                  float* __restrict__ csB, float* __restrict__ cqB)
{
    int i = blockIdx.x * 256 + threadIdx.x;
    float ht = tg[t + 1] - tg[t];
    if (i < BATCH) {
        float v = vt[i] - frow[i] * ht + dotrow[i];
        vt[i] = v;
        outv[i] = v;
        frow[i] = 0.0f;
        dotrow[i] = 0.0f;
    }
    if (i < HP) { csA[i] = 0.0f; cqA[i] = 0.0f; csB[i] = 0.0f; cqB[i] = 0.0f; }
}

// init: xt = x (in d_out region), zero accumulators
__global__ __launch_bounds__(256)
void init_k(const float* __restrict__ x, float* __restrict__ xt,
            float* __restrict__ frow, float* __restrict__ dotrow,
            float* __restrict__ csA, float* __restrict__ cqA,
            float* __restrict__ csB, float* __restrict__ cqB,
            float* __restrict__ s3, float* __restrict__ q3)
{
    int i = blockIdx.x * 256 + threadIdx.x;
    if (i < BATCH * DDIM) xt[i] = x[i];
    if (i < BATCH) { frow[i] = 0.0f; dotrow[i] = 0.0f; }
    if (i < HP) { csA[i] = 0.0f; cqA[i] = 0.0f; csB[i] = 0.0f; cqB[i] = 0.0f; }
    if (i == 0) { s3[0] = 0.0f; q3[0] = 0.0f; }
}

extern "C" void kernel_launch(void* const* d_in, const int* in_sizes, int n_in,
                              void* d_out, int out_size, void* d_ws, size_t ws_size,
                              hipStream_t stream)
{
    const float* x    = (const float*)d_in[0];
    const float* xi   = (const float*)d_in[1];
    const float* tg   = (const float*)d_in[2];
    const float* W1   = (const float*)d_in[3];
    const float* b1   = (const float*)d_in[4];
    const float* g1   = (const float*)d_in[5];
    const float* be1  = (const float*)d_in[6];
    const float* W2   = (const float*)d_in[7];
    const float* b2   = (const float*)d_in[8];
    const float* g2   = (const float*)d_in[9];
    const float* be2  = (const float*)d_in[10];
    const float* W3   = (const float*)d_in[11];
    const float* b3   = (const float*)d_in[12];
    const float* vW1  = (const float*)d_in[13];
    const float* vb1  = (const float*)d_in[14];
    const float* vg1  = (const float*)d_in[15];
    const float* vbe1 = (const float*)d_in[16];
    const float* vW2  = (const float*)d_in[17];
    const float* vb2  = (const float*)d_in[18];
    const float* vg2  = (const float*)d_in[19];
    const float* vbe2 = (const float*)d_in[20];
    const float* vW3  = (const float*)d_in[21];
    const float* vb3  = (const float*)d_in[22];
    const float* vg3  = (const float*)d_in[23];
    const float* vbe3 = (const float*)d_in[24];

    float* out = (float*)d_out;        // [0,B): vT ; [B, B + B*D): xT
    float* xt  = out + BATCH;

    float* ws     = (float*)d_ws;
    float* hpre1  = ws;
    float* hpre2  = hpre1 + (size_t)BATCH * HP;
    float* vt     = hpre2 + (size_t)BATCH * HP;
    float* frow   = vt + BATCH;
    float* dotrow = frow + BATCH;
    float* pre3   = dotrow + BATCH;
    float* csA    = pre3 + BATCH;
    float* cqA    = csA + HP;
    float* csB    = cqA + HP;
    float* cqB    = csB + HP;
    float* s3     = cqB + HP;
    float* q3     = s3 + 1;

    dim3 blk(256);
    dim3 gInit((BATCH * DDIM + 255) / 256);
    dim3 gH(5, 128);   // N=266 -> 5 col tiles, M=8192 -> 128 row tiles
    dim3 gD(4, 128);   // N=256 -> 4 col tiles

    init_k<<<gInit, blk, 0, stream>>>(x, xt, frow, dotrow, csA, cqA, csB, cqB, s3, q3);

    // v0 sub-network on x
    gemm_stats_k<false><<<gH, blk, 0, stream>>>(x, DDIM, DDIM, vW1, DDIM, vb1, HDIM,
                                                nullptr, nullptr, nullptr, nullptr,
                                                hpre1, HP, csA, cqA);
    gemm_stats_k<true><<<gH, blk, 0, stream>>>(hpre1, HP, HDIM, vW2, HDIM, vb2, HDIM,
                                               csA, cqA, vg1, vbe1,
                                               hpre2, HP, csB, cqB);
    vrow_k<<<dim3(BATCH / 4), blk, 0, stream>>>(hpre2, csB, cqB, vg2, vbe2, vW3, vb3,
                                                pre3, s3, q3);
    v3b_k<<<dim3(32), blk, 0, stream>>>(pre3, s3, q3, vg3, vbe3, vt, csA, cqA, csB, cqB);

    // scan over T steps
    for (int t = 0; t < TSTEPS; ++t) {
        gemm_stats_k<false><<<gH, blk, 0, stream>>>(
            xt, DDIM, DDIM, W1 + (size_t)t * HDIM * DDIM, DDIM, b1 + t * HDIM, HDIM,
            nullptr, nullptr, nullptr, nullptr, hpre1, HP, csA, cqA);
        gemm_stats_k<true><<<gH, blk, 0, stream>>>(
            hpre1, HP, HDIM, W2 + (size_t)t * HDIM * HDIM, HDIM, b2 + t * HDIM, HDIM,
            csA, cqA, g1 + t * HDIM, be1 + t * HDIM, hpre2, HP, csB, cqB);
        gemm_step3_k<<<gD, blk, 0, stream>>>(
            hpre2, W3 + (size_t)t * DDIM * HDIM, b3 + t * DDIM,
            csB, cqB, g2 + t * HDIM, be2 + t * HDIM,
            xi + (size_t)t * BATCH * DDIM, xt, frow, dotrow, tg, t);
        step_final_k<<<dim3(32), blk, 0, stream>>>(
            tg, t, vt, frow, dotrow, out, csA, cqA, csB, cqB);
    }
}

// Round 2
// 1909.268 us; speedup vs baseline: 1.8336x; 1.8336x over previous
//
#include <hip/hip_runtime.h>
#include <math.h>

#define BATCH 8192
#define DDIM 256
#define HDIM 266
#define HP 272          // bf16 row stride for hidden buffers (16B-aligned rows)
#define TSTEPS 20
#define BN_EPS 1e-5f
#define LAMBDA_C 1.0f
#define SIGMA_C 1.0f
#define LSTR 40         // LDS tile row stride in bf16 elements (80B -> bank-even)

typedef __attribute__((ext_vector_type(8))) short short8;   // 8 bf16
typedef __attribute__((ext_vector_type(4))) float f32x4;

__device__ __forceinline__ short f2bf(float f) {
    union { float f; unsigned u; } v; v.f = f;
    unsigned r = v.u + 0x7fffu + ((v.u >> 16) & 1u);   // RNE
    return (short)(r >> 16);
}
__device__ __forceinline__ float bf2f(short s) {
    union { unsigned u; float f; } v;
    v.u = ((unsigned)(unsigned short)s) << 16;
    return v.f;
}

// ---------------------------------------------------------------------------
// bf16-MFMA GEMM: C[M,N] = act(A) @ W^T + bias, M=8192. 64x64 block tile,
// BK=32, 256 threads = 4 waves, each wave a 32x32 quadrant (2x2 MFMA tiles).
// HID=false: A is fp32 (K=256, no BN). HID=true: A is bf16 hidden pre-act,
// BN+ReLU applied from column stats while staging (K=HDIM).
// Epilogue: store bf16 C (pre-BN) + accumulate column sum/sumsq via atomics.
// ---------------------------------------------------------------------------
template<bool HID>
__global__ __launch_bounds__(256)
void gemm_mfma_k(const void* __restrict__ Aptr, int lda, int Kdim,
                 const float* __restrict__ W, int ldw,
                 const float* __restrict__ bias, int Ndim,
                 const float* __restrict__ csum_in, const float* __restrict__ csq_in,
                 const float* __restrict__ gin, const float* __restrict__ bein,
                 short* __restrict__ C, int ldc,
                 float* __restrict__ csum_out, float* __restrict__ csq_out)
{
    __shared__ __align__(16) short As[64 * LSTR];
    __shared__ __align__(16) short Ws[64 * LSTR];
    __shared__ float sBN[HP];
    __shared__ float tBN[HP];

    const int tid  = threadIdx.x;
    const int col0 = blockIdx.x * 64;
    const int row0 = blockIdx.y * 64;

    if (HID) {
        for (int k = tid; k < Kdim; k += 256) {
            float mn = csum_in[k] * (1.0f / BATCH);
            float vr = csq_in[k] * (1.0f / BATCH) - mn * mn;
            float rs = rsqrtf(fmaxf(vr, 0.0f) + BN_EPS);
            float s  = gin[k] * rs;
            sBN[k] = s;
            tBN[k] = bein[k] - mn * s;
        }
        __syncthreads();
    }

    const int lane = tid & 63;
    const int w    = tid >> 6;
    const int q    = lane >> 4;
    const int m    = lane & 15;
    const int wr   = (w >> 1) * 32;
    const int wc   = (w & 1) * 32;

    const int srow = tid >> 2;        // staging row 0..63
    const int k0   = (tid & 3) * 8;   // staging k-offset within chunk

    f32x4 acc[2][2];
    #pragma unroll
    for (int i = 0; i < 2; ++i)
        #pragma unroll
        for (int j = 0; j < 2; ++j)
            acc[i][j] = (f32x4){0.f, 0.f, 0.f, 0.f};

    const int kTiles = (Kdim + 31) >> 5;
    for (int kt = 0; kt < kTiles; ++kt) {
        const int kg = kt * 32 + k0;

        // ---- stage A tile ----
        short8 av;
        if (!HID) {
            const float* ap = (const float*)Aptr + (size_t)(row0 + srow) * lda + kg;
            f32x4 p0 = *(const f32x4*)ap;
            f32x4 p1 = *(const f32x4*)(ap + 4);
            #pragma unroll
            for (int j = 0; j < 4; ++j) { av[j] = f2bf(p0[j]); av[4 + j] = f2bf(p1[j]); }
        } else {
            const short* ap = (const short*)Aptr + (size_t)(row0 + srow) * lda + kg;
            if (kg + 8 <= Kdim) {
                short8 raw = *(const short8*)ap;
                #pragma unroll
                for (int j = 0; j < 8; ++j) {
                    float f = bf2f(raw[j]);
                    f = fmaxf(f * sBN[kg + j] + tBN[kg + j], 0.0f);
                    av[j] = f2bf(f);
                }
            } else {
                #pragma unroll
                for (int j = 0; j < 8; ++j) {
                    int k = kg + j;
                    float f = 0.0f;
                    if (k < Kdim) {
                        f = bf2f(ap[j]);
                        f = fmaxf(f * sBN[k] + tBN[k], 0.0f);
                    }
                    av[j] = f2bf(f);
                }
            }
        }
        *(short8*)&As[srow * LSTR + k0] = av;

        // ---- stage W tile (fp32 global, possibly unaligned ldw) ----
        short8 wv;
        const int nrow = col0 + srow;
        if (nrow < Ndim) {
            const float* wp = W + (size_t)nrow * ldw + kg;
            #pragma unroll
            for (int j = 0; j < 8; ++j) {
                int k = kg + j;
                wv[j] = (k < Kdim) ? f2bf(wp[j]) : (short)0;
            }
        } else {
            #pragma unroll
            for (int j = 0; j < 8; ++j) wv[j] = 0;
        }
        *(short8*)&Ws[srow * LSTR + k0] = wv;

        __syncthreads();

        // ---- MFMA ----
        short8 a0 = *(const short8*)&As[(wr + m) * LSTR + q * 8];
        short8 a1 = *(const short8*)&As[(wr + 16 + m) * LSTR + q * 8];
        short8 b0 = *(const short8*)&Ws[(wc + m) * LSTR + q * 8];
        short8 b1 = *(const short8*)&Ws[(wc + 16 + m) * LSTR + q * 8];
        acc[0][0] = __builtin_amdgcn_mfma_f32_16x16x32_bf16(a0, b0, acc[0][0], 0, 0, 0);
        acc[0][1] = __builtin_amdgcn_mfma_f32_16x16x32_bf16(a0, b1, acc[0][1], 0, 0, 0);
        acc[1][0] = __builtin_amdgcn_mfma_f32_16x16x32_bf16(a1, b0, acc[1][0], 0, 0, 0);
        acc[1][1] = __builtin_amdgcn_mfma_f32_16x16x32_bf16(a1, b1, acc[1][1], 0, 0, 0);

        __syncthreads();
    }

    // ---- epilogue: bias, bf16 store, column stats ----
    float cs[2], cq[2];
    #pragma unroll
    for (int j = 0; j < 2; ++j) {
        const int col = col0 + wc + j * 16 + m;
        const bool cok = (col < Ndim);
        const float bv = cok ? bias[col] : 0.0f;
        float s = 0.0f, sq = 0.0f;
        #pragma unroll
        for (int i = 0; i < 2; ++i) {
            #pragma unroll
            for (int r = 0; r < 4; ++r) {
                float v = acc[i][j][r] + bv;
                int row = row0 + wr + i * 16 + q * 4 + r;
                if (cok) C[(size_t)row * ldc + col] = f2bf(v);
                s += v;
                sq += v * v;
            }
        }
        cs[j] = s; cq[j] = sq;
    }
    // reduce across q (lanes differing in bits 4,5 share a column)
    #pragma unroll
    for (int j = 0; j < 2; ++j) {
        cs[j] += __shfl_xor(cs[j], 16); cs[j] += __shfl_xor(cs[j], 32);
        cq[j] += __shfl_xor(cq[j], 16); cq[j] += __shfl_xor(cq[j], 32);
    }
    float* reds = (float*)As;   // 128 floats
    float* redq = (float*)Ws;   // 128 floats
    if (q == 0) {
        #pragma unroll
        for (int j = 0; j < 2; ++j) {
            reds[(w >> 1) * 64 + wc + j * 16 + m] = cs[j];
            redq[(w >> 1) * 64 + wc + j * 16 + m] = cq[j];
        }
    }
    __syncthreads();
    if (tid < 64) {
        int col = col0 + tid;
        if (col < Ndim) {
            atomicAdd(&csum_out[col], reds[tid] + reds[64 + tid]);
            atomicAdd(&csq_out[col],  redq[tid] + redq[64 + tid]);
        }
    }
}

// ---------------------------------------------------------------------------
// Step layer 3 (bf16 MFMA): grad = bnrelu(h2) @ W3^T + b3 (N=256), then SDE:
//   noise = sigma*sqrt(ht)*xi; xt += -sqrt(L)*grad*ht + noise
//   ftab[row] += L*grad^2 ; dtab[row] += grad*noise   (per-step tables)
// ---------------------------------------------------------------------------
__global__ __launch_bounds__(256)
void gemm_step3_k(const short* __restrict__ A,        // hpre2 bf16, stride HP
                  const float* __restrict__ W,        // W3_t [DDIM, HDIM]
                  const float* __restrict__ bias,     // b3_t [DDIM]
                  const float* __restrict__ csum_in, const float* __restrict__ csq_in,
                  const float* __restrict__ gin, const float* __restrict__ bein,
                  const float* __restrict__ xi_t,     // [BATCH, DDIM]
                  float* __restrict__ xt,             // [BATCH, DDIM] (in d_out)
                  float* __restrict__ ftab, float* __restrict__ dtab,
                  const float* __restrict__ tg, int t)
{
    __shared__ __align__(16) short As[64 * LSTR];
    __shared__ __align__(16) short Ws[64 * LSTR];
    __shared__ float sBN[HP];
    __shared__ float tBN[HP];

    const int tid  = threadIdx.x;
    const int col0 = blockIdx.x * 64;
    const int row0 = blockIdx.y * 64;
    const int Kdim = HDIM;

    for (int k = tid; k < Kdim; k += 256) {
        float mn = csum_in[k] * (1.0f / BATCH);
        float vr = csq_in[k] * (1.0f / BATCH) - mn * mn;
        float rs = rsqrtf(fmaxf(vr, 0.0f) + BN_EPS);
        float s  = gin[k] * rs;
        sBN[k] = s;
        tBN[k] = bein[k] - mn * s;
    }
    __syncthreads();

    const int lane = tid & 63;
    const int w    = tid >> 6;
    const int q    = lane >> 4;
    const int m    = lane & 15;
    const int wr   = (w >> 1) * 32;
    const int wc   = (w & 1) * 32;
    const int srow = tid >> 2;
    const int k0   = (tid & 3) * 8;

    f32x4 acc[2][2];
    #pragma unroll
    for (int i = 0; i < 2; ++i)
        #pragma unroll
        for (int j = 0; j < 2; ++j)
            acc[i][j] = (f32x4){0.f, 0.f, 0.f, 0.f};

    const int kTiles = (Kdim + 31) >> 5;   // 9
    for (int kt = 0; kt < kTiles; ++kt) {
        const int kg = kt * 32 + k0;

        short8 av;
        const short* ap = A + (size_t)(row0 + srow) * HP + kg;
        if (kg + 8 <= Kdim) {
            short8 raw = *(const short8*)ap;
            #pragma unroll
            for (int j = 0; j < 8; ++j) {
                float f = bf2f(raw[j]);
                f = fmaxf(f * sBN[kg + j] + tBN[kg + j], 0.0f);
                av[j] = f2bf(f);
            }
        } else {
            #pragma unroll
            for (int j = 0; j < 8; ++j) {
                int k = kg + j;
                float f = 0.0f;
                if (k < Kdim) {
                    f = bf2f(ap[j]);
                    f = fmaxf(f * sBN[k] + tBN[k], 0.0f);
                }
                av[j] = f2bf(f);
            }
        }
        *(short8*)&As[srow * LSTR + k0] = av;

        short8 wv;
        {
            const float* wp = W + (size_t)(col0 + srow) * HDIM + kg;  // all cols valid (N=256)
            #pragma unroll
            for (int j = 0; j < 8; ++j) {
                int k = kg + j;
                wv[j] = (k < Kdim) ? f2bf(wp[j]) : (short)0;
            }
        }
        *(short8*)&Ws[srow * LSTR + k0] = wv;

        __syncthreads();

        short8 a0 = *(const short8*)&As[(wr + m) * LSTR + q * 8];
        short8 a1 = *(const short8*)&As[(wr + 16 + m) * LSTR + q * 8];
        short8 b0 = *(const short8*)&Ws[(wc + m) * LSTR + q * 8];
        short8 b1 = *(const short8*)&Ws[(wc + 16 + m) * LSTR + q * 8];
        acc[0][0] = __builtin_amdgcn_mfma_f32_16x16x32_bf16(a0, b0, acc[0][0], 0, 0, 0);
        acc[0][1] = __builtin_amdgcn_mfma_f32_16x16x32_bf16(a0, b1, acc[0][1], 0, 0, 0);
        acc[1][0] = __builtin_amdgcn_mfma_f32_16x16x32_bf16(a1, b0, acc[1][0], 0, 0, 0);
        acc[1][1] = __builtin_amdgcn_mfma_f32_16x16x32_bf16(a1, b1, acc[1][1], 0, 0, 0);

        __syncthreads();
    }

    const float ht  = tg[t + 1] - tg[t];
    const float sn  = SIGMA_C * sqrtf(ht);
    const float sql = sqrtf(LAMBDA_C);

    float fp[2][4], dp[2][4];
    #pragma unroll
    for (int i = 0; i < 2; ++i) {
        #pragma unroll
        for (int r = 0; r < 4; ++r) {
            const int row = row0 + wr + i * 16 + q * 4 + r;
            float fr = 0.0f, dr = 0.0f;
            #pragma unroll
            for (int j = 0; j < 2; ++j) {
                const int col = col0 + wc + j * 16 + m;
                float grad = acc[i][j][r] + bias[col];
                size_t idx = (size_t)row * DDIM + col;
                float noise = sn * xi_t[idx];
                xt[idx] = xt[idx] - sql * grad * ht + noise;
                fr += LAMBDA_C * grad * grad;
                dr += grad * noise;
            }
            fp[i][r] = fr; dp[i][r] = dr;
        }
    }
    // reduce across m (lanes 0..15 within quad share rows)
    #pragma unroll
    for (int i = 0; i < 2; ++i)
        #pragma unroll
        for (int r = 0; r < 4; ++r) {
            fp[i][r] += __shfl_xor(fp[i][r], 1); dp[i][r] += __shfl_xor(dp[i][r], 1);
            fp[i][r] += __shfl_xor(fp[i][r], 2); dp[i][r] += __shfl_xor(dp[i][r], 2);
            fp[i][r] += __shfl_xor(fp[i][r], 4); dp[i][r] += __shfl_xor(dp[i][r], 4);
            fp[i][r] += __shfl_xor(fp[i][r], 8); dp[i][r] += __shfl_xor(dp[i][r], 8);
        }
    float* redf = (float*)As;   // 128 floats
    float* redd = (float*)Ws;   // 128 floats
    if (m == 0) {
        #pragma unroll
        for (int i = 0; i < 2; ++i)
            #pragma unroll
            for (int r = 0; r < 4; ++r) {
                redf[(w & 1) * 64 + wr + i * 16 + q * 4 + r] = fp[i][r];
                redd[(w & 1) * 64 + wr + i * 16 + q * 4 + r] = dp[i][r];
            }
    }
    __syncthreads();
    if (tid < 64) {
        atomicAdd(&ftab[row0 + tid], redf[tid] + redf[64 + tid]);
        atomicAdd(&dtab[row0 + tid], redd[tid] + redd[64 + tid]);
    }
}

// ---------------------------------------------------------------------------
// v-net layer 3: pre3[i] = bnrelu(h2v)[i,:] . vW3 + vb3 (one wave per row)
// ---------------------------------------------------------------------------
__global__ __launch_bounds__(256)
void vrow_k(const short* __restrict__ hpre2,
            const float* __restrict__ csum_in, const float* __restrict__ csq_in,
            const float* __restrict__ gin, const float* __restrict__ bein,
            const float* __restrict__ vW3, const float* __restrict__ vb3,
            float* __restrict__ pre3, float* __restrict__ sum3, float* __restrict__ sumsq3)
{
    __shared__ float sBN[HDIM];
    __shared__ float tBN[HDIM];
    __shared__ float wred[8];
    const int tid = threadIdx.x;
    for (int k = tid; k < HDIM; k += 256) {
        float mn = csum_in[k] * (1.0f / BATCH);
        float vr = csq_in[k] * (1.0f / BATCH) - mn * mn;
        float rs = rsqrtf(fmaxf(vr, 0.0f) + BN_EPS);
        float s  = gin[k] * rs;
        sBN[k] = s;
        tBN[k] = bein[k] - mn * s;
    }
    __syncthreads();
    const int wave = tid >> 6, lane = tid & 63;
    const int row = blockIdx.x * 4 + wave;
    float sum = 0.0f;
    for (int k = lane; k < HDIM; k += 64) {
        float v = fmaxf(bf2f(hpre2[(size_t)row * HP + k]) * sBN[k] + tBN[k], 0.0f);
        sum += v * vW3[k];
    }
    sum += __shfl_xor(sum, 1);  sum += __shfl_xor(sum, 2);
    sum += __shfl_xor(sum, 4);  sum += __shfl_xor(sum, 8);
    sum += __shfl_xor(sum, 16); sum += __shfl_xor(sum, 32);
    if (lane == 0) {
        float p = sum + vb3[0];
        pre3[row] = p;
        wred[wave] = p;
        wred[4 + wave] = p * p;
    }
    __syncthreads();
    if (tid == 0) {
        atomicAdd(sum3,   wred[0] + wred[1] + wred[2] + wred[3]);
        atomicAdd(sumsq3, wred[4] + wred[5] + wred[6] + wred[7]);
    }
}

__global__ __launch_bounds__(256)
void v3b_k(const float* __restrict__ pre3,
           const float* __restrict__ sum3, const float* __restrict__ sumsq3,
           const float* __restrict__ vg3, const float* __restrict__ vbe3,
           float* __restrict__ vt)
{
    int i = blockIdx.x * 256 + threadIdx.x;
    float mn = sum3[0] * (1.0f / BATCH);
    float va = fmaxf(sumsq3[0] * (1.0f / BATCH) - mn * mn, 0.0f);
    float rs = rsqrtf(va + BN_EPS);
    if (i < BATCH) vt[i] = fmaxf(vg3[0] * (pre3[i] - mn) * rs + vbe3[0], 0.0f);
}

// final: vT[i] = v0[i] + sum_t (dot_t[i] - f_t[i]*ht_t)
__global__ __launch_bounds__(256)
void final_v_k(const float* __restrict__ vt,
               const float* __restrict__ ftab, const float* __restrict__ dtab,
               const float* __restrict__ tg, float* __restrict__ outv)
{
    int i = blockIdx.x * 256 + threadIdx.x;
    if (i >= BATCH) return;
    float v = vt[i];
    for (int t = 0; t < TSTEPS; ++t) {
        float ht = tg[t + 1] - tg[t];
        v += dtab[(size_t)t * BATCH + i] - ftab[(size_t)t * BATCH + i] * ht;
    }
    outv[i] = v;
}

// init: xt = x; zero the accumulation region (ftab..q3)
__global__ __launch_bounds__(256)
void init_k(const float* __restrict__ x, float* __restrict__ xt,
            float* __restrict__ zbase, int zcount)
{
    int i = blockIdx.x * 256 + threadIdx.x;
    if (i < BATCH * DDIM) xt[i] = x[i];
    if (i < zcount) zbase[i] = 0.0f;
}

extern "C" void kernel_launch(void* const* d_in, const int* in_sizes, int n_in,
                              void* d_out, int out_size, void* d_ws, size_t ws_size,
                              hipStream_t stream)
{
    const float* x    = (const float*)d_in[0];
    const float* xi   = (const float*)d_in[1];
    const float* tg   = (const float*)d_in[2];
    const float* W1   = (const float*)d_in[3];
    const float* b1   = (const float*)d_in[4];
    const float* g1   = (const float*)d_in[5];
    const float* be1  = (const float*)d_in[6];
    const float* W2   = (const float*)d_in[7];
    const float* b2   = (const float*)d_in[8];
    const float* g2   = (const float*)d_in[9];
    const float* be2  = (const float*)d_in[10];
    const float* W3   = (const float*)d_in[11];
    const float* b3   = (const float*)d_in[12];
    const float* vW1  = (const float*)d_in[13];
    const float* vb1  = (const float*)d_in[14];
    const float* vg1  = (const float*)d_in[15];
    const float* vbe1 = (const float*)d_in[16];
    const float* vW2  = (const float*)d_in[17];
    const float* vb2  = (const float*)d_in[18];
    const float* vg2  = (const float*)d_in[19];
    const float* vbe2 = (const float*)d_in[20];
    const float* vW3  = (const float*)d_in[21];
    const float* vb3  = (const float*)d_in[22];
    const float* vg3  = (const float*)d_in[23];
    const float* vbe3 = (const float*)d_in[24];

    float* out = (float*)d_out;        // [0,B): vT ; [B, B + B*D): xT
    float* xt  = out + BATCH;

    // workspace layout
    short* hp1 = (short*)d_ws;                         // BATCH*HP bf16
    short* hp2 = hp1 + (size_t)BATCH * HP;             // BATCH*HP bf16
    float* fb  = (float*)(hp2 + (size_t)BATCH * HP);
    float* vt   = fb;                    // BATCH
    float* pre3 = vt + BATCH;            // BATCH
    float* ftab = pre3 + BATCH;          // TSTEPS*BATCH
    float* dtab = ftab + (size_t)TSTEPS * BATCH;
    float* csA  = dtab + (size_t)TSTEPS * BATCH;  // 21*HP (slot 20 = v-net)
    float* cqA  = csA + 21 * HP;
    float* csB  = cqA + 21 * HP;
    float* cqB  = csB + 21 * HP;
    float* s3   = cqB + 21 * HP;
    float* q3   = s3 + 1;
    const int zcount = 2 * TSTEPS * BATCH + 4 * 21 * HP + 2;  // ftab..q3 contiguous

    dim3 blk(256);
    dim3 gInit((BATCH * DDIM + 255) / 256);
    dim3 gH(5, BATCH / 64);   // N=266 -> 5 col tiles
    dim3 gD(4, BATCH / 64);   // N=256 -> 4 col tiles

    init_k<<<gInit, blk, 0, stream>>>(x, xt, ftab, zcount);

    // v0 sub-network (stat slot 20)
    float* csV1 = csA + 20 * HP; float* cqV1 = cqA + 20 * HP;
    float* csV2 = csB + 20 * HP; float* cqV2 = cqB + 20 * HP;
    gemm_mfma_k<false><<<gH, blk, 0, stream>>>(x, DDIM, DDIM, vW1, DDIM, vb1, HDIM,
                                               nullptr, nullptr, nullptr, nullptr,
                                               hp1, HP, csV1, cqV1);
    gemm_mfma_k<true><<<gH, blk, 0, stream>>>(hp1, HP, HDIM, vW2, HDIM, vb2, HDIM,
                                              csV1, cqV1, vg1, vbe1,
                                              hp2, HP, csV2, cqV2);
    vrow_k<<<dim3(BATCH / 4), blk, 0, stream>>>(hp2, csV2, cqV2, vg2, vbe2, vW3, vb3,
                                                pre3, s3, q3);
    v3b_k<<<dim3(BATCH / 256), blk, 0, stream>>>(pre3, s3, q3, vg3, vbe3, vt);

    // scan
    for (int t = 0; t < TSTEPS; ++t) {
        gemm_mfma_k<false><<<gH, blk, 0, stream>>>(
            xt, DDIM, DDIM, W1 + (size_t)t * HDIM * DDIM, DDIM, b1 + t * HDIM, HDIM,
            nullptr, nullptr, nullptr, nullptr, hp1, HP, csA + t * HP, cqA + t * HP);
        gemm_mfma_k<true><<<gH, blk, 0, stream>>>(
            hp1, HP, HDIM, W2 + (size_t)t * HDIM * HDIM, HDIM, b2 + t * HDIM, HDIM,
            csA + t * HP, cqA + t * HP, g1 + t * HDIM, be1 + t * HDIM,
            hp2, HP, csB + t * HP, cqB + t * HP);
        gemm_step3_k<<<gD, blk, 0, stream>>>(
            hp2, W3 + (size_t)t * DDIM * HDIM, b3 + t * DDIM,
            csB + t * HP, cqB + t * HP, g2 + t * HDIM, be2 + t * HDIM,
            xi + (size_t)t * BATCH * DDIM, xt,
            ftab + (size_t)t * BATCH, dtab + (size_t)t * BATCH, tg, t);
    }
    final_v_k<<<dim3(BATCH / 256), blk, 0, stream>>>(vt, ftab, dtab, tg, out);
}

// Round 3
// 1174.965 us; speedup vs baseline: 2.9796x; 1.6250x over previous
//
#include <hip/hip_runtime.h>
#include <hip/hip_bf16.h>
#include <math.h>

#define BATCH 8192
#define DDIM 256
#define HDIM 266
#define NPAD 320        // padded N (and padded K for H-sized dims)
#define TSTEPS 20
#define BN_EPS 1e-5f
#define LAMBDA_C 1.0f
#define SIGMA_C 1.0f
#define LSTR 72         // LDS tile row stride in shorts (144 B: 2-way bank = free)

typedef __attribute__((ext_vector_type(8))) short short8;   // 8 bf16
typedef __attribute__((ext_vector_type(4))) float f32x4;

__device__ __forceinline__ short f2bf(float f) {
    __hip_bfloat16 h = __float2bfloat16(f);
    return *reinterpret_cast<short*>(&h);
}
__device__ __forceinline__ float bf2f(short s) {
    union { unsigned u; float f; } v;
    v.u = ((unsigned)(unsigned short)s) << 16;
    return v.f;
}

// ---------------------------------------------------------------------------
// Weight pad+convert: dst[t][r][k] (bf16, r<Npad, k<Kpad) = src[t][r][k] or 0
// ---------------------------------------------------------------------------
__global__ __launch_bounds__(256)
void pad_w_k(short* __restrict__ dst, const float* __restrict__ src,
             int total, int Npad, int N, int Kpad, int K)
{
    int idx = blockIdx.x * 256 + threadIdx.x;
    if (idx >= total) return;
    int k = idx % Kpad;
    int r = (idx / Kpad) % Npad;
    int t = idx / (Kpad * Npad);
    float v = (r < N && k < K) ? src[((size_t)t * N + r) * K + k] : 0.0f;
    dst[idx] = f2bf(v);
}

// fp32 pad: dst[t][n] = src[t][n] or 0
__global__ __launch_bounds__(256)
void pad_b_k(float* __restrict__ dst, const float* __restrict__ src,
             int total, int Npad, int N)
{
    int idx = blockIdx.x * 256 + threadIdx.x;
    if (idx >= total) return;
    int n = idx % Npad;
    int t = idx / Npad;
    dst[idx] = (n < N) ? src[(size_t)t * N + n] : 0.0f;
}

// init: xt = x (fp32), xtb = bf16(x), zero accumulator region
__global__ __launch_bounds__(256)
void init_k(const float* __restrict__ x, float* __restrict__ xt,
            short* __restrict__ xtb, float* __restrict__ zbase, int zcount)
{
    int i = blockIdx.x * 256 + threadIdx.x;
    if (i < BATCH * DDIM) { float v = x[i]; xt[i] = v; xtb[i] = f2bf(v); }
    if (i < zcount) zbase[i] = 0.0f;
}

// ---------------------------------------------------------------------------
// Pure bf16 MFMA GEMM: C[M,Ngrid*64] = A @ W^T + biasp. 64x64 tile, BK=64,
// 256 thr = 4 waves (2x2 quadrants of 32x32, 2x2 MFMA each). No bounds checks
// (all operands zero-padded). Epilogue: bf16 C + column sum/sumsq atomics.
// ---------------------------------------------------------------------------
__global__ __launch_bounds__(256)
void gemm_k(const short* __restrict__ A, int lda, int ktn,
            const short* __restrict__ W, int ldw,
            const float* __restrict__ biasp,
            short* __restrict__ C, int ldc,
            float* __restrict__ csum_out, float* __restrict__ csq_out, int nstats)
{
    __shared__ __align__(16) short As[64 * LSTR];
    __shared__ __align__(16) short Bs[64 * LSTR];

    const int tid  = threadIdx.x;
    const int col0 = blockIdx.x * 64;
    const int row0 = blockIdx.y * 64;
    const int lane = tid & 63;
    const int w    = tid >> 6;
    const int q    = lane >> 4;
    const int m    = lane & 15;
    const int wr   = (w >> 1) * 32;
    const int wc   = (w & 1) * 32;
    const int srow = tid >> 2;
    const int kq   = (tid & 3) * 8;

    f32x4 acc[2][2];
    #pragma unroll
    for (int i = 0; i < 2; ++i)
        #pragma unroll
        for (int j = 0; j < 2; ++j) acc[i][j] = (f32x4){0.f, 0.f, 0.f, 0.f};

    for (int kt = 0; kt < ktn; ++kt) {
        const int kg = kt * 64 + kq;
        const short* ap = A + (size_t)(row0 + srow) * lda + kg;
        const short* wp = W + (size_t)(col0 + srow) * ldw + kg;
        short8 a0 = *(const short8*)ap;
        short8 a1 = *(const short8*)(ap + 32);
        short8 w0 = *(const short8*)wp;
        short8 w1 = *(const short8*)(wp + 32);
        *(short8*)&As[srow * LSTR + kq]      = a0;
        *(short8*)&As[srow * LSTR + kq + 32] = a1;
        *(short8*)&Bs[srow * LSTR + kq]      = w0;
        *(short8*)&Bs[srow * LSTR + kq + 32] = w1;
        __syncthreads();

        #pragma unroll
        for (int kk = 0; kk < 2; ++kk) {
            short8 fa0 = *(const short8*)&As[(wr + m)      * LSTR + q * 8 + kk * 32];
            short8 fa1 = *(const short8*)&As[(wr + 16 + m) * LSTR + q * 8 + kk * 32];
            short8 fb0 = *(const short8*)&Bs[(wc + m)      * LSTR + q * 8 + kk * 32];
            short8 fb1 = *(const short8*)&Bs[(wc + 16 + m) * LSTR + q * 8 + kk * 32];
            acc[0][0] = __builtin_amdgcn_mfma_f32_16x16x32_bf16(fa0, fb0, acc[0][0], 0, 0, 0);
            acc[0][1] = __builtin_amdgcn_mfma_f32_16x16x32_bf16(fa0, fb1, acc[0][1], 0, 0, 0);
            acc[1][0] = __builtin_amdgcn_mfma_f32_16x16x32_bf16(fa1, fb0, acc[1][0], 0, 0, 0);
            acc[1][1] = __builtin_amdgcn_mfma_f32_16x16x32_bf16(fa1, fb1, acc[1][1], 0, 0, 0);
        }
        __syncthreads();
    }

    // epilogue: bias, bf16 store, column stats
    float cs[2], cq[2];
    #pragma unroll
    for (int j = 0; j < 2; ++j) {
        const int col = col0 + wc + j * 16 + m;
        const float bv = biasp[col];
        float s = 0.0f, sq = 0.0f;
        #pragma unroll
        for (int i = 0; i < 2; ++i)
            #pragma unroll
            for (int r = 0; r < 4; ++r) {
                float v = acc[i][j][r] + bv;
                int row = row0 + wr + i * 16 + q * 4 + r;
                C[(size_t)row * ldc + col] = f2bf(v);
                s += v; sq += v * v;
            }
        cs[j] = s; cq[j] = sq;
    }
    #pragma unroll
    for (int j = 0; j < 2; ++j) {
        cs[j] += __shfl_xor(cs[j], 16); cs[j] += __shfl_xor(cs[j], 32);
        cq[j] += __shfl_xor(cq[j], 16); cq[j] += __shfl_xor(cq[j], 32);
    }
    float* reds = (float*)As;
    float* redq = (float*)Bs;
    if (q == 0) {
        #pragma unroll
        for (int j = 0; j < 2; ++j) {
            reds[(w >> 1) * 64 + wc + j * 16 + m] = cs[j];
            redq[(w >> 1) * 64 + wc + j * 16 + m] = cq[j];
        }
    }
    __syncthreads();
    if (tid < 64) {
        int col = col0 + tid;
        if (col < nstats) {
            atomicAdd(&csum_out[col], reds[tid] + reds[64 + tid]);
            atomicAdd(&csq_out[col],  redq[tid] + redq[64 + tid]);
        }
    }
}

// ---------------------------------------------------------------------------
// In-place BN+ReLU on a [BATCH x NPAD] bf16 buffer; pad cols forced to zero.
// 256 blocks x 32 rows; short8 vectorized; scale/shift computed once in LDS.
// ---------------------------------------------------------------------------
__global__ __launch_bounds__(256)
void bn_k(short* __restrict__ act,
          const float* __restrict__ csum, const float* __restrict__ csq,
          const float* __restrict__ g, const float* __restrict__ be)
{
    __shared__ float sS[NPAD];
    __shared__ float sT[NPAD];
    const int tid = threadIdx.x;
    for (int k = tid; k < NPAD; k += 256) {
        float s = 0.0f, t = 0.0f;
        if (k < HDIM) {
            float mn = csum[k] * (1.0f / BATCH);
            float vr = csq[k] * (1.0f / BATCH) - mn * mn;
            float rs = rsqrtf(fmaxf(vr, 0.0f) + BN_EPS);
            s = g[k] * rs;
            t = be[k] - mn * s;
        }
        sS[k] = s; sT[k] = t;
    }
    __syncthreads();
    const size_t base = (size_t)blockIdx.x * 32 * NPAD;
    #pragma unroll
    for (int c = 0; c < 5; ++c) {
        int flat = c * 256 + tid;
        int r  = flat / 40;
        int c8 = (flat % 40) * 8;
        short8 v = *(short8*)&act[base + (size_t)r * NPAD + c8];
        #pragma unroll
        for (int j = 0; j < 8; ++j) {
            float f = bf2f(v[j]);
            f = fmaxf(f * sS[c8 + j] + sT[c8 + j], 0.0f);
            v[j] = f2bf(f);
        }
        *(short8*)&act[base + (size_t)r * NPAD + c8] = v;
    }
}

// ---------------------------------------------------------------------------
// Step layer 3: grad = a2 @ W3b^T + b3 (N=256), fused SDE epilogue:
//   noise = sigma*sqrt(ht)*xi; xt += -sqrt(L)*grad*ht + noise (fp32 + bf16)
//   ftab[row] += L*grad^2; dtab[row] += grad*noise
// ---------------------------------------------------------------------------
__global__ __launch_bounds__(256)
void gemm_step3_k(const short* __restrict__ A,       // a2 bf16 [B x NPAD]
                  const short* __restrict__ W,       // W3b [256 x NPAD]
                  const float* __restrict__ bias,    // b3_t [256] raw
                  const float* __restrict__ xi_t,    // [B x 256]
                  float* __restrict__ xt,            // fp32 (d_out)
                  short* __restrict__ xtb,           // bf16 mirror
                  float* __restrict__ ftab, float* __restrict__ dtab,
                  const float* __restrict__ tg, int t)
{
    __shared__ __align__(16) short As[64 * LSTR];
    __shared__ __align__(16) short Bs[64 * LSTR];

    const int tid  = threadIdx.x;
    const int col0 = blockIdx.x * 64;
    const int row0 = blockIdx.y * 64;
    const int lane = tid & 63;
    const int w    = tid >> 6;
    const int q    = lane >> 4;
    const int m    = lane & 15;
    const int wr   = (w >> 1) * 32;
    const int wc   = (w & 1) * 32;
    const int srow = tid >> 2;
    const int kq   = (tid & 3) * 8;

    f32x4 acc[2][2];
    #pragma unroll
    for (int i = 0; i < 2; ++i)
        #pragma unroll
        for (int j = 0; j < 2; ++j) acc[i][j] = (f32x4){0.f, 0.f, 0.f, 0.f};

    for (int kt = 0; kt < 5; ++kt) {
        const int kg = kt * 64 + kq;
        const short* ap = A + (size_t)(row0 + srow) * NPAD + kg;
        const short* wp = W + (size_t)(col0 + srow) * NPAD + kg;
        short8 a0 = *(const short8*)ap;
        short8 a1 = *(const short8*)(ap + 32);
        short8 w0 = *(const short8*)wp;
        short8 w1 = *(const short8*)(wp + 32);
        *(short8*)&As[srow * LSTR + kq]      = a0;
        *(short8*)&As[srow * LSTR + kq + 32] = a1;
        *(short8*)&Bs[srow * LSTR + kq]      = w0;
        *(short8*)&Bs[srow * LSTR + kq + 32] = w1;
        __syncthreads();

        #pragma unroll
        for (int kk = 0; kk < 2; ++kk) {
            short8 fa0 = *(const short8*)&As[(wr + m)      * LSTR + q * 8 + kk * 32];
            short8 fa1 = *(const short8*)&As[(wr + 16 + m) * LSTR + q * 8 + kk * 32];
            short8 fb0 = *(const short8*)&Bs[(wc + m)      * LSTR + q * 8 + kk * 32];
            short8 fb1 = *(const short8*)&Bs[(wc + 16 + m) * LSTR + q * 8 + kk * 32];
            acc[0][0] = __builtin_amdgcn_mfma_f32_16x16x32_bf16(fa0, fb0, acc[0][0], 0, 0, 0);
            acc[0][1] = __builtin_amdgcn_mfma_f32_16x16x32_bf16(fa0, fb1, acc[0][1], 0, 0, 0);
            acc[1][0] = __builtin_amdgcn_mfma_f32_16x16x32_bf16(fa1, fb0, acc[1][0], 0, 0, 0);
            acc[1][1] = __builtin_amdgcn_mfma_f32_16x16x32_bf16(fa1, fb1, acc[1][1], 0, 0, 0);
        }
        __syncthreads();
    }

    const float ht  = tg[t + 1] - tg[t];
    const float sn  = SIGMA_C * sqrtf(ht);
    const float sql = sqrtf(LAMBDA_C);

    float fp[2][4], dp[2][4];
    #pragma unroll
    for (int i = 0; i < 2; ++i)
        #pragma unroll
        for (int r = 0; r < 4; ++r) {
            const int row = row0 + wr + i * 16 + q * 4 + r;
            float fr = 0.0f, dr = 0.0f;
            #pragma unroll
            for (int j = 0; j < 2; ++j) {
                const int col = col0 + wc + j * 16 + m;
                float grad = acc[i][j][r] + bias[col];
                size_t idx = (size_t)row * DDIM + col;
                float noise = sn * xi_t[idx];
                float nx = xt[idx] - sql * grad * ht + noise;
                xt[idx] = nx;
                xtb[idx] = f2bf(nx);
                fr += LAMBDA_C * grad * grad;
                dr += grad * noise;
            }
            fp[i][r] = fr; dp[i][r] = dr;
        }
    #pragma unroll
    for (int i = 0; i < 2; ++i)
        #pragma unroll
        for (int r = 0; r < 4; ++r) {
            fp[i][r] += __shfl_xor(fp[i][r], 1); dp[i][r] += __shfl_xor(dp[i][r], 1);
            fp[i][r] += __shfl_xor(fp[i][r], 2); dp[i][r] += __shfl_xor(dp[i][r], 2);
            fp[i][r] += __shfl_xor(fp[i][r], 4); dp[i][r] += __shfl_xor(dp[i][r], 4);
            fp[i][r] += __shfl_xor(fp[i][r], 8); dp[i][r] += __shfl_xor(dp[i][r], 8);
        }
    float* redf = (float*)As;
    float* redd = (float*)Bs;
    if (m == 0) {
        #pragma unroll
        for (int i = 0; i < 2; ++i)
            #pragma unroll
            for (int r = 0; r < 4; ++r) {
                redf[(w & 1) * 64 + wr + i * 16 + q * 4 + r] = fp[i][r];
                redd[(w & 1) * 64 + wr + i * 16 + q * 4 + r] = dp[i][r];
            }
    }
    __syncthreads();
    if (tid < 64) {
        atomicAdd(&ftab[row0 + tid], redf[tid] + redf[64 + tid]);
        atomicAdd(&dtab[row0 + tid], redd[tid] + redd[64 + tid]);
    }
}

// v-net layer 3: pre3[i] = a2v[i,:] . vW3p + vb3 (one wave per row)
__global__ __launch_bounds__(256)
void vrow_k(const short* __restrict__ a2v,
            const float* __restrict__ vW3p, const float* __restrict__ vb3,
            float* __restrict__ pre3, float* __restrict__ sum3, float* __restrict__ sumsq3)
{
    __shared__ float wred[8];
    const int tid = threadIdx.x;
    const int wave = tid >> 6, lane = tid & 63;
    const int row = blockIdx.x * 4 + wave;
    float sum = 0.0f;
    #pragma unroll
    for (int c = 0; c < 5; ++c) {
        int k = c * 64 + lane;
        sum += bf2f(a2v[(size_t)row * NPAD + k]) * vW3p[k];
    }
    sum += __shfl_xor(sum, 1);  sum += __shfl_xor(sum, 2);
    sum += __shfl_xor(sum, 4);  sum += __shfl_xor(sum, 8);
    sum += __shfl_xor(sum, 16); sum += __shfl_xor(sum, 32);
    if (lane == 0) {
        float p = sum + vb3[0];
        pre3[row] = p;
        wred[wave] = p;
        wred[4 + wave] = p * p;
    }
    __syncthreads();
    if (tid == 0) {
        atomicAdd(sum3,   wred[0] + wred[1] + wred[2] + wred[3]);
        atomicAdd(sumsq3, wred[4] + wred[5] + wred[6] + wred[7]);
    }
}

__global__ __launch_bounds__(256)
void v3b_k(const float* __restrict__ pre3,
           const float* __restrict__ sum3, const float* __restrict__ sumsq3,
           const float* __restrict__ vg3, const float* __restrict__ vbe3,
           float* __restrict__ vt)
{
    int i = blockIdx.x * 256 + threadIdx.x;
    float mn = sum3[0] * (1.0f / BATCH);
    float va = fmaxf(sumsq3[0] * (1.0f / BATCH) - mn * mn, 0.0f);
    float rs = rsqrtf(va + BN_EPS);
    if (i < BATCH) vt[i] = fmaxf(vg3[0] * (pre3[i] - mn) * rs + vbe3[0], 0.0f);
}

// final: vT[i] = v0[i] + sum_t (dot_t[i] - f_t[i]*ht_t)
__global__ __launch_bounds__(256)
void final_v_k(const float* __restrict__ vt,
               const float* __restrict__ ftab, const float* __restrict__ dtab,
               const float* __restrict__ tg, float* __restrict__ outv)
{
    int i = blockIdx.x * 256 + threadIdx.x;
    if (i >= BATCH) return;
    float v = vt[i];
    for (int t = 0; t < TSTEPS; ++t) {
        float ht = tg[t + 1] - tg[t];
        v += dtab[(size_t)t * BATCH + i] - ftab[(size_t)t * BATCH + i] * ht;
    }
    outv[i] = v;
}

extern "C" void kernel_launch(void* const* d_in, const int* in_sizes, int n_in,
                              void* d_out, int out_size, void* d_ws, size_t ws_size,
                              hipStream_t stream)
{
    const float* x    = (const float*)d_in[0];
    const float* xi   = (const float*)d_in[1];
    const float* tg   = (const float*)d_in[2];
    const float* W1   = (const float*)d_in[3];
    const float* b1   = (const float*)d_in[4];
    const float* g1   = (const float*)d_in[5];
    const float* be1  = (const float*)d_in[6];
    const float* W2   = (const float*)d_in[7];
    const float* b2   = (const float*)d_in[8];
    const float* g2   = (const float*)d_in[9];
    const float* be2  = (const float*)d_in[10];
    const float* W3   = (const float*)d_in[11];
    const float* b3   = (const float*)d_in[12];
    const float* vW1  = (const float*)d_in[13];
    const float* vb1  = (const float*)d_in[14];
    const float* vg1  = (const float*)d_in[15];
    const float* vbe1 = (const float*)d_in[16];
    const float* vW2  = (const float*)d_in[17];
    const float* vb2  = (const float*)d_in[18];
    const float* vg2  = (const float*)d_in[19];
    const float* vbe2 = (const float*)d_in[20];
    const float* vW3  = (const float*)d_in[21];
    const float* vb3  = (const float*)d_in[22];
    const float* vg3  = (const float*)d_in[23];
    const float* vbe3 = (const float*)d_in[24];

    float* out = (float*)d_out;        // [0,B): vT ; [B, B + B*D): xT
    float* xt  = out + BATCH;

    // ---- workspace layout ----
    short* xtb  = (short*)d_ws;                          // B*256
    short* hp1  = xtb + (size_t)BATCH * DDIM;            // B*NPAD
    short* hp2  = hp1 + (size_t)BATCH * NPAD;            // B*NPAD
    short* W1b  = hp2 + (size_t)BATCH * NPAD;            // 20*320*256
    short* W2b  = W1b + (size_t)TSTEPS * NPAD * DDIM;    // 20*320*320
    short* W3b  = W2b + (size_t)TSTEPS * NPAD * NPAD;    // 20*256*320
    short* vW1b = W3b + (size_t)TSTEPS * DDIM * NPAD;    // 320*256
    short* vW2b = vW1b + (size_t)NPAD * DDIM;            // 320*320
    float* fbase = (float*)(vW2b + (size_t)NPAD * NPAD);
    float* b1p  = fbase;                 // 20*320
    float* b2p  = b1p + TSTEPS * NPAD;   // 20*320
    float* vb1p = b2p + TSTEPS * NPAD;   // 320
    float* vb2p = vb1p + NPAD;           // 320
    float* vW3p = vb2p + NPAD;           // 320
    float* vt   = vW3p + NPAD;           // B
    float* pre3 = vt + BATCH;            // B
    float* ftab = pre3 + BATCH;          // 20*B   (zero region starts here)
    float* dtab = ftab + (size_t)TSTEPS * BATCH;
    float* csA  = dtab + (size_t)TSTEPS * BATCH;   // 21*NPAD (slot 20 = v-net)
    float* cqA  = csA + 21 * NPAD;
    float* csB  = cqA + 21 * NPAD;
    float* cqB  = csB + 21 * NPAD;
    float* s3   = cqB + 21 * NPAD;
    float* q3   = s3 + 1;
    const int zcount = 2 * TSTEPS * BATCH + 4 * 21 * NPAD + 2;

    dim3 blk(256);
    dim3 gH(5, BATCH / 64);   // N=320 padded
    dim3 gD(4, BATCH / 64);   // N=256

    // ---- one-time prep (same work every call) ----
    init_k<<<dim3((BATCH * DDIM + 255) / 256), blk, 0, stream>>>(x, xt, xtb, ftab, zcount);
    {
        int tot;
        tot = TSTEPS * NPAD * DDIM;
        pad_w_k<<<dim3((tot + 255) / 256), blk, 0, stream>>>(W1b, W1, tot, NPAD, HDIM, DDIM, DDIM);
        tot = TSTEPS * NPAD * NPAD;
        pad_w_k<<<dim3((tot + 255) / 256), blk, 0, stream>>>(W2b, W2, tot, NPAD, HDIM, NPAD, HDIM);
        tot = TSTEPS * DDIM * NPAD;
        pad_w_k<<<dim3((tot + 255) / 256), blk, 0, stream>>>(W3b, W3, tot, DDIM, DDIM, NPAD, HDIM);
        tot = NPAD * DDIM;
        pad_w_k<<<dim3((tot + 255) / 256), blk, 0, stream>>>(vW1b, vW1, tot, NPAD, HDIM, DDIM, DDIM);
        tot = NPAD * NPAD;
        pad_w_k<<<dim3((tot + 255) / 256), blk, 0, stream>>>(vW2b, vW2, tot, NPAD, HDIM, NPAD, HDIM);
        tot = TSTEPS * NPAD;
        pad_b_k<<<dim3((tot + 255) / 256), blk, 0, stream>>>(b1p, b1, tot, NPAD, HDIM);
        pad_b_k<<<dim3((tot + 255) / 256), blk, 0, stream>>>(b2p, b2, tot, NPAD, HDIM);
        pad_b_k<<<dim3(2), blk, 0, stream>>>(vb1p, vb1, NPAD, NPAD, HDIM);
        pad_b_k<<<dim3(2), blk, 0, stream>>>(vb2p, vb2, NPAD, NPAD, HDIM);
        pad_b_k<<<dim3(2), blk, 0, stream>>>(vW3p, vW3, NPAD, NPAD, HDIM);
    }

    // ---- v0 sub-network (stat slot 20) ----
    float* csV1 = csA + 20 * NPAD; float* cqV1 = cqA + 20 * NPAD;
    float* csV2 = csB + 20 * NPAD; float* cqV2 = cqB + 20 * NPAD;
    gemm_k<<<gH, blk, 0, stream>>>(xtb, DDIM, 4, vW1b, DDIM, vb1p, hp1, NPAD, csV1, cqV1, HDIM);
    bn_k<<<dim3(256), blk, 0, stream>>>(hp1, csV1, cqV1, vg1, vbe1);
    gemm_k<<<gH, blk, 0, stream>>>(hp1, NPAD, 5, vW2b, NPAD, vb2p, hp2, NPAD, csV2, cqV2, HDIM);
    bn_k<<<dim3(256), blk, 0, stream>>>(hp2, csV2, cqV2, vg2, vbe2);
    vrow_k<<<dim3(BATCH / 4), blk, 0, stream>>>(hp2, vW3p, vb3, pre3, s3, q3);
    v3b_k<<<dim3(BATCH / 256), blk, 0, stream>>>(pre3, s3, q3, vg3, vbe3, vt);

    // ---- scan ----
    for (int t = 0; t < TSTEPS; ++t) {
        gemm_k<<<gH, blk, 0, stream>>>(
            xtb, DDIM, 4, W1b + (size_t)t * NPAD * DDIM, DDIM, b1p + t * NPAD,
            hp1, NPAD, csA + t * NPAD, cqA + t * NPAD, HDIM);
        bn_k<<<dim3(256), blk, 0, stream>>>(hp1, csA + t * NPAD, cqA + t * NPAD,
                                            g1 + t * HDIM, be1 + t * HDIM);
        gemm_k<<<gH, blk, 0, stream>>>(
            hp1, NPAD, 5, W2b + (size_t)t * NPAD * NPAD, NPAD, b2p + t * NPAD,
            hp2, NPAD, csB + t * NPAD, cqB + t * NPAD, HDIM);
        bn_k<<<dim3(256), blk, 0, stream>>>(hp2, csB + t * NPAD, cqB + t * NPAD,
                                            g2 + t * HDIM, be2 + t * HDIM);
        gemm_step3_k<<<gD, blk, 0, stream>>>(
            hp2, W3b + (size_t)t * DDIM * NPAD, b3 + t * DDIM,
            xi + (size_t)t * BATCH * DDIM, xt, xtb,
            ftab + (size_t)t * BATCH, dtab + (size_t)t * BATCH, tg, t);
    }
    final_v_k<<<dim3(BATCH / 256), blk, 0, stream>>>(vt, ftab, dtab, tg, out);
}

// Round 4
// 1143.822 us; speedup vs baseline: 3.0607x; 1.0272x over previous
//
#include <hip/hip_runtime.h>
#include <hip/hip_bf16.h>
#include <math.h>

#define BATCH 8192
#define DDIM 256
#define HDIM 266
#define NPAD 320
#define TSTEPS 20
#define BN_EPS 1e-5f
#define LSTR 72         // LDS row stride in shorts (144 B; even bank spread for b128)

typedef __attribute__((ext_vector_type(8))) short short8;   // 8 bf16
typedef __attribute__((ext_vector_type(4))) float f32x4;

__device__ __forceinline__ short f2bf(float f) {
    __hip_bfloat16 h = __float2bfloat16(f);
    return *reinterpret_cast<short*>(&h);
}
__device__ __forceinline__ float bf2f(short s) {
    union { unsigned u; float f; } v;
    v.u = ((unsigned)(unsigned short)s) << 16;
    return v.f;
}

// ---------------------------------------------------------------------------
// Merged prep: pad+convert all weights (bf16) and biases (fp32) in one kernel.
// ---------------------------------------------------------------------------
#define SZ_W1B (20L * 320 * 256)
#define SZ_W2B (20L * 320 * 320)
#define SZ_W3B (20L * 256 * 320)
#define SZ_VW1 (320L * 256)
#define SZ_VW2 (320L * 320)
#define SZ_B1P (20L * 320)
#define SZ_B2P (20L * 320)
#define PREP_TOTAL (SZ_W1B + SZ_W2B + SZ_W3B + SZ_VW1 + SZ_VW2 + SZ_B1P + SZ_B2P + 3 * 320)

__global__ __launch_bounds__(256)
void prep_k(short* __restrict__ W1b, const float* __restrict__ W1,
            short* __restrict__ W2b, const float* __restrict__ W2,
            short* __restrict__ W3b, const float* __restrict__ W3,
            short* __restrict__ vW1b, const float* __restrict__ vW1,
            short* __restrict__ vW2b, const float* __restrict__ vW2,
            float* __restrict__ b1p, const float* __restrict__ b1,
            float* __restrict__ b2p, const float* __restrict__ b2,
            float* __restrict__ vb1p, const float* __restrict__ vb1,
            float* __restrict__ vb2p, const float* __restrict__ vb2,
            float* __restrict__ vW3p, const float* __restrict__ vW3)
{
    long idx = (long)blockIdx.x * 256 + threadIdx.x;
    if (idx < SZ_W1B) {  // [20][320][256], src [20][266][256]
        long k = idx % 256, r = (idx / 256) % 320, t = idx / (256L * 320);
        float v = (r < HDIM) ? W1[((size_t)t * HDIM + r) * 256 + k] : 0.0f;
        W1b[idx] = f2bf(v); return;
    }
    idx -= SZ_W1B;
    if (idx < SZ_W2B) {  // [20][320][320], src [20][266][266]
        long k = idx % 320, r = (idx / 320) % 320, t = idx / (320L * 320);
        float v = (r < HDIM && k < HDIM) ? W2[((size_t)t * HDIM + r) * HDIM + k] : 0.0f;
        W2b[idx] = f2bf(v); return;
    }
    idx -= SZ_W2B;
    if (idx < SZ_W3B) {  // [20][256][320], src [20][256][266]
        long k = idx % 320, r = (idx / 320) % 256, t = idx / (320L * 256);
        float v = (k < HDIM) ? W3[((size_t)t * 256 + r) * HDIM + k] : 0.0f;
        W3b[idx] = f2bf(v); return;
    }
    idx -= SZ_W3B;
    if (idx < SZ_VW1) {  // [320][256], src [266][256]
        long k = idx % 256, r = idx / 256;
        float v = (r < HDIM) ? vW1[(size_t)r * 256 + k] : 0.0f;
        vW1b[idx] = f2bf(v); return;
    }
    idx -= SZ_VW1;
    if (idx < SZ_VW2) {  // [320][320], src [266][266]
        long k = idx % 320, r = idx / 320;
        float v = (r < HDIM && k < HDIM) ? vW2[(size_t)r * HDIM + k] : 0.0f;
        vW2b[idx] = f2bf(v); return;
    }
    idx -= SZ_VW2;
    if (idx < SZ_B1P) { long n = idx % 320, t = idx / 320;
        b1p[idx] = (n < HDIM) ? b1[(size_t)t * HDIM + n] : 0.0f; return; }
    idx -= SZ_B1P;
    if (idx < SZ_B2P) { long n = idx % 320, t = idx / 320;
        b2p[idx] = (n < HDIM) ? b2[(size_t)t * HDIM + n] : 0.0f; return; }
    idx -= SZ_B2P;
    if (idx < 320) { vb1p[idx] = (idx < HDIM) ? vb1[idx] : 0.0f; return; }
    idx -= 320;
    if (idx < 320) { vb2p[idx] = (idx < HDIM) ? vb2[idx] : 0.0f; return; }
    idx -= 320;
    if (idx < 320) { vW3p[idx] = (idx < HDIM) ? vW3[idx] : 0.0f; return; }
}

// init: xtb = bf16(x); zero the accumulator region
__global__ __launch_bounds__(256)
void init_k(const float* __restrict__ x, short* __restrict__ xtb,
            float* __restrict__ zbase, int zcount)
{
    int i = blockIdx.x * 256 + threadIdx.x;
    if (i < BATCH * DDIM) xtb[i] = f2bf(x[i]);
    if (i < zcount) zbase[i] = 0.0f;
}

// ---------------------------------------------------------------------------
// GEMM1 (pure): C[B,320] = A[B,256] @ W[320,256]^T + biasp. 64x64 tile, BK=64,
// reg-prefetch. Epilogue: bf16 C + column sum/sumsq (cols < HDIM).
// ---------------------------------------------------------------------------
__global__ __launch_bounds__(256)
void gemm1_k(const short* __restrict__ A, const short* __restrict__ W,
             const float* __restrict__ biasp, short* __restrict__ C,
             float* __restrict__ csum, float* __restrict__ csq)
{
    __shared__ __align__(16) short As[64 * LSTR];
    __shared__ __align__(16) short Bs[64 * LSTR];
    const int tid = threadIdx.x;
    const int col0 = blockIdx.x * 64, row0 = blockIdx.y * 64;
    const int lane = tid & 63, w = tid >> 6, q = lane >> 4, m = lane & 15;
    const int wr = (w >> 1) * 32, wc = (w & 1) * 32;
    const int srow = tid >> 2, kq = (tid & 3) * 8;

    const short* ap = A + (size_t)(row0 + srow) * DDIM + kq;
    const short* wp = W + (size_t)(col0 + srow) * DDIM + kq;
    short8 ra0 = *(const short8*)ap;
    short8 ra1 = *(const short8*)(ap + 32);
    short8 rw0 = *(const short8*)wp;
    short8 rw1 = *(const short8*)(wp + 32);

    f32x4 acc[2][2];
    #pragma unroll
    for (int i = 0; i < 2; ++i)
        #pragma unroll
        for (int j = 0; j < 2; ++j) acc[i][j] = (f32x4){0.f, 0.f, 0.f, 0.f};

    #pragma unroll
    for (int kt = 0; kt < 4; ++kt) {
        *(short8*)&As[srow * LSTR + kq]      = ra0;
        *(short8*)&As[srow * LSTR + kq + 32] = ra1;
        *(short8*)&Bs[srow * LSTR + kq]      = rw0;
        *(short8*)&Bs[srow * LSTR + kq + 32] = rw1;
        __syncthreads();
        if (kt < 3) {
            ap += 64; wp += 64;
            ra0 = *(const short8*)ap; ra1 = *(const short8*)(ap + 32);
            rw0 = *(const short8*)wp; rw1 = *(const short8*)(wp + 32);
        }
        #pragma unroll
        for (int kk = 0; kk < 2; ++kk) {
            short8 fa0 = *(const short8*)&As[(wr + m)      * LSTR + kk * 32 + q * 8];
            short8 fa1 = *(const short8*)&As[(wr + 16 + m) * LSTR + kk * 32 + q * 8];
            short8 fb0 = *(const short8*)&Bs[(wc + m)      * LSTR + kk * 32 + q * 8];
            short8 fb1 = *(const short8*)&Bs[(wc + 16 + m) * LSTR + kk * 32 + q * 8];
            acc[0][0] = __builtin_amdgcn_mfma_f32_16x16x32_bf16(fa0, fb0, acc[0][0], 0, 0, 0);
            acc[0][1] = __builtin_amdgcn_mfma_f32_16x16x32_bf16(fa0, fb1, acc[0][1], 0, 0, 0);
            acc[1][0] = __builtin_amdgcn_mfma_f32_16x16x32_bf16(fa1, fb0, acc[1][0], 0, 0, 0);
            acc[1][1] = __builtin_amdgcn_mfma_f32_16x16x32_bf16(fa1, fb1, acc[1][1], 0, 0, 0);
        }
        __syncthreads();
    }

    float cs[2], cq[2];
    #pragma unroll
    for (int j = 0; j < 2; ++j) {
        const int col = col0 + wc + j * 16 + m;
        const float bv = biasp[col];
        float s = 0.0f, sq = 0.0f;
        #pragma unroll
        for (int i = 0; i < 2; ++i)
            #pragma unroll
            for (int r = 0; r < 4; ++r) {
                float v = acc[i][j][r] + bv;
                int row = row0 + wr + i * 16 + q * 4 + r;
                C[(size_t)row * NPAD + col] = f2bf(v);
                s += v; sq += v * v;
            }
        cs[j] = s; cq[j] = sq;
    }
    #pragma unroll
    for (int j = 0; j < 2; ++j) {
        cs[j] += __shfl_xor(cs[j], 16); cs[j] += __shfl_xor(cs[j], 32);
        cq[j] += __shfl_xor(cq[j], 16); cq[j] += __shfl_xor(cq[j], 32);
    }
    float* reds = (float*)As;
    float* redq = (float*)Bs;
    if (q == 0) {
        #pragma unroll
        for (int j = 0; j < 2; ++j) {
            reds[(w >> 1) * 64 + wc + j * 16 + m] = cs[j];
            redq[(w >> 1) * 64 + wc + j * 16 + m] = cq[j];
        }
    }
    __syncthreads();
    if (tid < 64) {
        int col = col0 + tid;
        if (col < HDIM) {
            atomicAdd(&csum[col], reds[tid] + reds[64 + tid]);
            atomicAdd(&csq[col],  redq[tid] + redq[64 + tid]);
        }
    }
}

// ---------------------------------------------------------------------------
// GEMM2 (BN-staged A): C[B,320] = bnrelu(A)[B,320] @ W[320,320]^T + biasp.
// 32x160 tile, BK=64, reg-prefetch. Waves: (rowhalf=w>>1)*16 rows x
// (colhalf=w&1)*80 cols, 5 MFMA col-tiles each.
// ---------------------------------------------------------------------------
__global__ __launch_bounds__(256)
void gemm2_k(const short* __restrict__ A, const short* __restrict__ W,
             const float* __restrict__ biasp,
             const float* __restrict__ csum_in, const float* __restrict__ csq_in,
             const float* __restrict__ g, const float* __restrict__ be,
             short* __restrict__ C,
             float* __restrict__ csum_out, float* __restrict__ csq_out)
{
    __shared__ __align__(16) short As[32 * LSTR];
    __shared__ __align__(16) short Bs[160 * LSTR];
    __shared__ float sS[NPAD], sT[NPAD];
    const int tid = threadIdx.x;
    for (int k = tid; k < NPAD; k += 256) {
        float s = 0.0f, t = 0.0f;
        if (k < HDIM) {
            float mn = csum_in[k] * (1.0f / BATCH);
            float vr = csq_in[k] * (1.0f / BATCH) - mn * mn;
            float rs = rsqrtf(fmaxf(vr, 0.0f) + BN_EPS);
            s = g[k] * rs;
            t = be[k] - mn * s;
        }
        sS[k] = s; sT[k] = t;
    }
    __syncthreads();

    const int col0 = blockIdx.x * 160, row0 = blockIdx.y * 32;
    const int lane = tid & 63, w = tid >> 6, q = lane >> 4, m = lane & 15;
    const int rh = w >> 1, ch = w & 1;
    const int srowA = tid >> 3, kqA = (tid & 7) * 8;

    const short* ap = A + (size_t)(row0 + srowA) * NPAD + kqA;
    short8 rA = *(const short8*)ap;
    short8 rB[5];
    #pragma unroll
    for (int i = 0; i < 5; ++i) {
        int s = tid + 256 * i;
        rB[i] = *(const short8*)(W + (size_t)(col0 + (s >> 3)) * NPAD + ((s & 7) * 8));
    }

    f32x4 acc[5];
    #pragma unroll
    for (int j = 0; j < 5; ++j) acc[j] = (f32x4){0.f, 0.f, 0.f, 0.f};

    #pragma unroll
    for (int kt = 0; kt < 5; ++kt) {
        short8 ta;
        const int kb = kt * 64 + kqA;
        #pragma unroll
        for (int j = 0; j < 8; ++j) {
            float f = bf2f(rA[j]);
            f = fmaxf(f * sS[kb + j] + sT[kb + j], 0.0f);
            ta[j] = f2bf(f);
        }
        *(short8*)&As[srowA * LSTR + kqA] = ta;
        #pragma unroll
        for (int i = 0; i < 5; ++i) {
            int s = tid + 256 * i;
            *(short8*)&Bs[(s >> 3) * LSTR + (s & 7) * 8] = rB[i];
        }
        __syncthreads();
        if (kt < 4) {
            ap += 64;
            rA = *(const short8*)ap;
            #pragma unroll
            for (int i = 0; i < 5; ++i) {
                int s = tid + 256 * i;
                rB[i] = *(const short8*)(W + (size_t)(col0 + (s >> 3)) * NPAD
                                         + (kt + 1) * 64 + ((s & 7) * 8));
            }
        }
        #pragma unroll
        for (int kk = 0; kk < 2; ++kk) {
            short8 fa = *(const short8*)&As[(rh * 16 + m) * LSTR + kk * 32 + q * 8];
            #pragma unroll
            for (int j = 0; j < 5; ++j) {
                short8 fb = *(const short8*)&Bs[(ch * 80 + j * 16 + m) * LSTR + kk * 32 + q * 8];
                acc[j] = __builtin_amdgcn_mfma_f32_16x16x32_bf16(fa, fb, acc[j], 0, 0, 0);
            }
        }
        __syncthreads();
    }

    float csv[5], cqv[5];
    #pragma unroll
    for (int j = 0; j < 5; ++j) {
        const int col = col0 + ch * 80 + j * 16 + m;
        const float bv = biasp[col];
        float s = 0.0f, sq = 0.0f;
        #pragma unroll
        for (int r = 0; r < 4; ++r) {
            float v = acc[j][r] + bv;
            int row = row0 + rh * 16 + q * 4 + r;
            C[(size_t)row * NPAD + col] = f2bf(v);
            s += v; sq += v * v;
        }
        csv[j] = s; cqv[j] = sq;
    }
    #pragma unroll
    for (int j = 0; j < 5; ++j) {
        csv[j] += __shfl_xor(csv[j], 16); csv[j] += __shfl_xor(csv[j], 32);
        cqv[j] += __shfl_xor(cqv[j], 16); cqv[j] += __shfl_xor(cqv[j], 32);
    }
    float* redS = (float*)As;          // 640 floats needed; As = 4608 B
    float* redQ = redS + 320;
    if (q == 0) {
        #pragma unroll
        for (int j = 0; j < 5; ++j) {
            redS[rh * 160 + ch * 80 + j * 16 + m] = csv[j];
            redQ[rh * 160 + ch * 80 + j * 16 + m] = cqv[j];
        }
    }
    __syncthreads();
    if (tid < 160) {
        int col = col0 + tid;
        if (col < HDIM) {
            atomicAdd(&csum_out[col], redS[tid] + redS[160 + tid]);
            atomicAdd(&csq_out[col],  redQ[tid] + redQ[160 + tid]);
        }
    }
}

// ---------------------------------------------------------------------------
// GEMM3 (BN-staged A + SDE epilogue): grad[B,256] = bnrelu(A) @ W[256,320]^T
// + b3. 32x128 tile, BK=64. Epilogue updates xtb (bf16), writes fp32 xT on
// the last step, and accumulates ftab/dtab per row.
// ---------------------------------------------------------------------------
__global__ __launch_bounds__(256)
void gemm3_k(const short* __restrict__ A, const short* __restrict__ W,
             const float* __restrict__ bias,
             const float* __restrict__ csum_in, const float* __restrict__ csq_in,
             const float* __restrict__ g, const float* __restrict__ be,
             const float* __restrict__ xi_t,
             short* __restrict__ xtb, float* __restrict__ xout,
             float* __restrict__ ftab, float* __restrict__ dtab,
             const float* __restrict__ tg, int t, int last)
{
    __shared__ __align__(16) short As[32 * LSTR];
    __shared__ __align__(16) short Bs[128 * LSTR];
    __shared__ float sS[NPAD], sT[NPAD];
    const int tid = threadIdx.x;
    for (int k = tid; k < NPAD; k += 256) {
        float s = 0.0f, tt = 0.0f;
        if (k < HDIM) {
            float mn = csum_in[k] * (1.0f / BATCH);
            float vr = csq_in[k] * (1.0f / BATCH) - mn * mn;
            float rs = rsqrtf(fmaxf(vr, 0.0f) + BN_EPS);
            s = g[k] * rs;
            tt = be[k] - mn * s;
        }
        sS[k] = s; sT[k] = tt;
    }
    __syncthreads();

    const int col0 = blockIdx.x * 128, row0 = blockIdx.y * 32;
    const int lane = tid & 63, w = tid >> 6, q = lane >> 4, m = lane & 15;
    const int rh = w >> 1, ch = w & 1;
    const int srowA = tid >> 3, kqA = (tid & 7) * 8;

    const short* ap = A + (size_t)(row0 + srowA) * NPAD + kqA;
    short8 rA = *(const short8*)ap;
    short8 rB[4];
    #pragma unroll
    for (int i = 0; i < 4; ++i) {
        int s = tid + 256 * i;
        rB[i] = *(const short8*)(W + (size_t)(col0 + (s >> 3)) * NPAD + ((s & 7) * 8));
    }

    f32x4 acc[4];
    #pragma unroll
    for (int j = 0; j < 4; ++j) acc[j] = (f32x4){0.f, 0.f, 0.f, 0.f};

    #pragma unroll
    for (int kt = 0; kt < 5; ++kt) {
        short8 ta;
        const int kb = kt * 64 + kqA;
        #pragma unroll
        for (int j = 0; j < 8; ++j) {
            float f = bf2f(rA[j]);
            f = fmaxf(f * sS[kb + j] + sT[kb + j], 0.0f);
            ta[j] = f2bf(f);
        }
        *(short8*)&As[srowA * LSTR + kqA] = ta;
        #pragma unroll
        for (int i = 0; i < 4; ++i) {
            int s = tid + 256 * i;
            *(short8*)&Bs[(s >> 3) * LSTR + (s & 7) * 8] = rB[i];
        }
        __syncthreads();
        if (kt < 4) {
            ap += 64;
            rA = *(const short8*)ap;
            #pragma unroll
            for (int i = 0; i < 4; ++i) {
                int s = tid + 256 * i;
                rB[i] = *(const short8*)(W + (size_t)(col0 + (s >> 3)) * NPAD
                                         + (kt + 1) * 64 + ((s & 7) * 8));
            }
        }
        #pragma unroll
        for (int kk = 0; kk < 2; ++kk) {
            short8 fa = *(const short8*)&As[(rh * 16 + m) * LSTR + kk * 32 + q * 8];
            #pragma unroll
            for (int j = 0; j < 4; ++j) {
                short8 fb = *(const short8*)&Bs[(ch * 64 + j * 16 + m) * LSTR + kk * 32 + q * 8];
                acc[j] = __builtin_amdgcn_mfma_f32_16x16x32_bf16(fa, fb, acc[j], 0, 0, 0);
            }
        }
        __syncthreads();
    }

    // SDE epilogue (LAMBDA=1, SIGMA=1): alpha=-grad; f=|grad|^2; noise=sqrt(ht)*xi
    const float ht = tg[t + 1] - tg[t];
    const float sn = sqrtf(ht);
    float fr[4] = {0.f, 0.f, 0.f, 0.f};
    float dr[4] = {0.f, 0.f, 0.f, 0.f};
    #pragma unroll
    for (int j = 0; j < 4; ++j) {
        const int col = col0 + ch * 64 + j * 16 + m;
        const float bv = bias[col];
        #pragma unroll
        for (int r = 0; r < 4; ++r) {
            const int row = row0 + rh * 16 + q * 4 + r;
            size_t idx = (size_t)row * DDIM + col;
            float grad = acc[j][r] + bv;
            float noise = sn * xi_t[idx];
            float nx = bf2f(xtb[idx]) - grad * ht + noise;
            xtb[idx] = f2bf(nx);
            if (last) xout[idx] = nx;
            fr[r] += grad * grad;
            dr[r] += grad * noise;
        }
    }
    #pragma unroll
    for (int r = 0; r < 4; ++r) {
        fr[r] += __shfl_xor(fr[r], 1); dr[r] += __shfl_xor(dr[r], 1);
        fr[r] += __shfl_xor(fr[r], 2); dr[r] += __shfl_xor(dr[r], 2);
        fr[r] += __shfl_xor(fr[r], 4); dr[r] += __shfl_xor(dr[r], 4);
        fr[r] += __shfl_xor(fr[r], 8); dr[r] += __shfl_xor(dr[r], 8);
    }
    if (m == 0) {
        #pragma unroll
        for (int r = 0; r < 4; ++r) {
            const int row = row0 + rh * 16 + q * 4 + r;
            atomicAdd(&ftab[row], fr[r]);
            atomicAdd(&dtab[row], dr[r]);
        }
    }
}

// v-net layer 3: pre3[i] = bnrelu(hp2)[i,:] . vW3p + vb3 (one wave per row)
__global__ __launch_bounds__(256)
void vrow_k(const short* __restrict__ A,
            const float* __restrict__ csum_in, const float* __restrict__ csq_in,
            const float* __restrict__ g, const float* __restrict__ be,
            const float* __restrict__ vW3p, const float* __restrict__ vb3,
            float* __restrict__ pre3, float* __restrict__ s3, float* __restrict__ q3)
{
    __shared__ float sS[NPAD], sT[NPAD];
    __shared__ float wred[8];
    const int tid = threadIdx.x;
    for (int k = tid; k < NPAD; k += 256) {
        float s = 0.0f, t = 0.0f;
        if (k < HDIM) {
            float mn = csum_in[k] * (1.0f / BATCH);
            float vr = csq_in[k] * (1.0f / BATCH) - mn * mn;
            float rs = rsqrtf(fmaxf(vr, 0.0f) + BN_EPS);
            s = g[k] * rs;
            t = be[k] - mn * s;
        }
        sS[k] = s; sT[k] = t;
    }
    __syncthreads();
    const int wave = tid >> 6, lane = tid & 63;
    const int row = blockIdx.x * 4 + wave;
    float sum = 0.0f;
    #pragma unroll
    for (int c = 0; c < 5; ++c) {
        int k = c * 64 + lane;
        float v = fmaxf(bf2f(A[(size_t)row * NPAD + k]) * sS[k] + sT[k], 0.0f);
        sum += v * vW3p[k];
    }
    sum += __shfl_xor(sum, 1);  sum += __shfl_xor(sum, 2);
    sum += __shfl_xor(sum, 4);  sum += __shfl_xor(sum, 8);
    sum += __shfl_xor(sum, 16); sum += __shfl_xor(sum, 32);
    if (lane == 0) {
        float p = sum + vb3[0];
        pre3[row] = p;
        wred[wave] = p;
        wred[4 + wave] = p * p;
    }
    __syncthreads();
    if (tid == 0) {
        atomicAdd(s3, wred[0] + wred[1] + wred[2] + wred[3]);
        atomicAdd(q3, wred[4] + wred[5] + wred[6] + wred[7]);
    }
}

__global__ __launch_bounds__(256)
void v3b_k(const float* __restrict__ pre3,
           const float* __restrict__ s3, const float* __restrict__ q3,
           const float* __restrict__ vg3, const float* __restrict__ vbe3,
           float* __restrict__ vt)
{
    int i = blockIdx.x * 256 + threadIdx.x;
    float mn = s3[0] * (1.0f / BATCH);
    float va = fmaxf(q3[0] * (1.0f / BATCH) - mn * mn, 0.0f);
    float rs = rsqrtf(va + BN_EPS);
    if (i < BATCH) vt[i] = fmaxf(vg3[0] * (pre3[i] - mn) * rs + vbe3[0], 0.0f);
}

// final: vT[i] = v0[i] + sum_t (dot_t[i] - f_t[i]*ht_t)
__global__ __launch_bounds__(256)
void final_v_k(const float* __restrict__ vt,
               const float* __restrict__ ftab, const float* __restrict__ dtab,
               const float* __restrict__ tg, float* __restrict__ outv)
{
    int i = blockIdx.x * 256 + threadIdx.x;
    if (i >= BATCH) return;
    float v = vt[i];
    for (int t = 0; t < TSTEPS; ++t) {
        float ht = tg[t + 1] - tg[t];
        v += dtab[(size_t)t * BATCH + i] - ftab[(size_t)t * BATCH + i] * ht;
    }
    outv[i] = v;
}

extern "C" void kernel_launch(void* const* d_in, const int* in_sizes, int n_in,
                              void* d_out, int out_size, void* d_ws, size_t ws_size,
                              hipStream_t stream)
{
    const float* x    = (const float*)d_in[0];
    const float* xi   = (const float*)d_in[1];
    const float* tg   = (const float*)d_in[2];
    const float* W1   = (const float*)d_in[3];
    const float* b1   = (const float*)d_in[4];
    const float* g1   = (const float*)d_in[5];
    const float* be1  = (const float*)d_in[6];
    const float* W2   = (const float*)d_in[7];
    const float* b2   = (const float*)d_in[8];
    const float* g2   = (const float*)d_in[9];
    const float* be2  = (const float*)d_in[10];
    const float* W3   = (const float*)d_in[11];
    const float* b3   = (const float*)d_in[12];
    const float* vW1  = (const float*)d_in[13];
    const float* vb1  = (const float*)d_in[14];
    const float* vg1  = (const float*)d_in[15];
    const float* vbe1 = (const float*)d_in[16];
    const float* vW2  = (const float*)d_in[17];
    const float* vb2  = (const float*)d_in[18];
    const float* vg2  = (const float*)d_in[19];
    const float* vbe2 = (const float*)d_in[20];
    const float* vW3  = (const float*)d_in[21];
    const float* vb3  = (const float*)d_in[22];
    const float* vg3  = (const float*)d_in[23];
    const float* vbe3 = (const float*)d_in[24];

    float* out  = (float*)d_out;       // [0,B): vT ; [B, B+B*D): xT (fp32)
    float* xout = out + BATCH;

    // ---- workspace layout (bf16 region first, then fp32) ----
    short* xtb  = (short*)d_ws;                          // B*256
    short* hp1  = xtb + (size_t)BATCH * DDIM;            // B*320
    short* hp2  = hp1 + (size_t)BATCH * NPAD;            // B*320
    short* W1b  = hp2 + (size_t)BATCH * NPAD;            // SZ_W1B
    short* W2b  = W1b + SZ_W1B;
    short* W3b  = W2b + SZ_W2B;
    short* vW1b = W3b + SZ_W3B;
    short* vW2b = vW1b + SZ_VW1;
    float* fbase = (float*)(vW2b + SZ_VW2);
    float* b1p  = fbase;                       // 20*320
    float* b2p  = b1p + TSTEPS * NPAD;         // 20*320
    float* vb1p = b2p + TSTEPS * NPAD;         // 320
    float* vb2p = vb1p + NPAD;                 // 320
    float* vW3p = vb2p + NPAD;                 // 320
    float* vt   = vW3p + NPAD;                 // B
    float* pre3 = vt + BATCH;                  // B
    float* ftab = pre3 + BATCH;                // 20*B  (zero region starts here)
    float* dtab = ftab + (size_t)TSTEPS * BATCH;
    float* csA  = dtab + (size_t)TSTEPS * BATCH;   // 21*NPAD (slot 20 = v-net)
    float* cqA  = csA + 21 * NPAD;
    float* csB  = cqA + 21 * NPAD;
    float* cqB  = csB + 21 * NPAD;
    float* s3   = cqB + 21 * NPAD;
    float* q3   = s3 + 1;
    const int zcount = 2 * TSTEPS * BATCH + 4 * 21 * NPAD + 2;

    dim3 blk(256);
    dim3 g1g(5, BATCH / 64);    // gemm1: 64x64 tiles, N=320
    dim3 g2g(2, BATCH / 32);    // gemm2: 32x160 tiles
    dim3 g3g(2, BATCH / 32);    // gemm3: 32x128 tiles

    init_k<<<dim3((BATCH * DDIM + 255) / 256), blk, 0, stream>>>(x, xtb, ftab, zcount);
    prep_k<<<dim3((int)((PREP_TOTAL + 255) / 256)), blk, 0, stream>>>(
        W1b, W1, W2b, W2, W3b, W3, vW1b, vW1, vW2b, vW2,
        b1p, b1, b2p, b2, vb1p, vb1, vb2p, vb2, vW3p, vW3);

    // ---- v0 sub-network (stat slot 20) ----
    float* csV1 = csA + 20 * NPAD; float* cqV1 = cqA + 20 * NPAD;
    float* csV2 = csB + 20 * NPAD; float* cqV2 = cqB + 20 * NPAD;
    gemm1_k<<<g1g, blk, 0, stream>>>(xtb, vW1b, vb1p, hp1, csV1, cqV1);
    gemm2_k<<<g2g, blk, 0, stream>>>(hp1, vW2b, vb2p, csV1, cqV1, vg1, vbe1,
                                     hp2, csV2, cqV2);
    vrow_k<<<dim3(BATCH / 4), blk, 0, stream>>>(hp2, csV2, cqV2, vg2, vbe2,
                                                vW3p, vb3, pre3, s3, q3);
    v3b_k<<<dim3(BATCH / 256), blk, 0, stream>>>(pre3, s3, q3, vg3, vbe3, vt);

    // ---- scan ----
    for (int t = 0; t < TSTEPS; ++t) {
        gemm1_k<<<g1g, blk, 0, stream>>>(
            xtb, W1b + (size_t)t * NPAD * DDIM, b1p + t * NPAD,
            hp1, csA + t * NPAD, cqA + t * NPAD);
        gemm2_k<<<g2g, blk, 0, stream>>>(
            hp1, W2b + (size_t)t * NPAD * NPAD, b2p + t * NPAD,
            csA + t * NPAD, cqA + t * NPAD, g1 + t * HDIM, be1 + t * HDIM,
            hp2, csB + t * NPAD, cqB + t * NPAD);
        gemm3_k<<<g3g, blk, 0, stream>>>(
            hp2, W3b + (size_t)t * DDIM * NPAD, b3 + t * DDIM,
            csB + t * NPAD, cqB + t * NPAD, g2 + t * HDIM, be2 + t * HDIM,
            xi + (size_t)t * BATCH * DDIM, xtb, xout,
            ftab + (size_t)t * BATCH, dtab + (size_t)t * BATCH,
            tg, t, (t == TSTEPS - 1) ? 1 : 0);
    }
    final_v_k<<<dim3(BATCH / 256), blk, 0, stream>>>(vt, ftab, dtab, tg, out);
}